// Round 8
// baseline (1476.366 us; speedup 1.0000x reference)
//
#include <hip/hip_runtime.h>
#include <hip/hip_bf16.h>

typedef int int4v __attribute__((ext_vector_type(4)));
typedef float float4v __attribute__((ext_vector_type(4)));
typedef _Float16 half8 __attribute__((ext_vector_type(8)));

#define DEV __device__ __forceinline__

DEV signed char quant8(float v) {
    int q = (int)rintf(v);
    q = q < -128 ? -128 : (q > 127 ? 127 : q);
    return (signed char)q;
}

DEV int tern1(float v) {
    int q = (int)rintf(v);
    q = q < -1 ? -1 : (q > 1 ? 1 : q);
    return q;
}

// async global->LDS, 16B per lane; LDS dest = wave-uniform base + lane*16
DEV void gl2lds16(const void* g, void* l) {
    __builtin_amdgcn_global_load_lds(
        (const __attribute__((address_space(1))) void*)g,
        (__attribute__((address_space(3))) void*)l, 16, 0, 0);
}

// wave-redundant absmean beta from the partial sums
DEV float beta_of(const double* __restrict__ part, int wi) {
    int offs = wi == 0 ? 0 : (wi == 1 ? 64 : (wi == 2 ? 96 : 128));
    int cnt  = (wi == 1 || wi == 2) ? 32 : 64;
    double invc = (wi == 1 || wi == 2) ? (1.0 / 524288.0) : (1.0 / 1048576.0);
    int lane = threadIdx.x & 63;
    double v = (lane < cnt) ? part[offs + lane] : 0.0;
    #pragma unroll
    for (int o = 32; o > 0; o >>= 1) v += __shfl_down(v, o);
    v = __shfl(v, 0);
    return fmaxf((float)(v * invc), 1e-5f);
}

// ------------------------------------------------- device-scope grid barrier
// Epoch barrier for a FULLY CO-RESIDENT grid (1024 blocks @ 4 blocks/CU,
// guaranteed by __launch_bounds__(256,4) + 32KB LDS). Arrive: ACQ_REL
// fetch-add on `in`; last arriver resets `in` and release-bumps `epoch`;
// waiters spin on acquire-load of `epoch` (emits L1 buffer_inv). Monotone
// epoch + graph-captured memset init keeps replays correct.
DEV void gridbar(unsigned* in, unsigned* ep, unsigned nblk) {
    __threadfence();
    __syncthreads();
    if (threadIdx.x == 0) {
        unsigned e = __hip_atomic_load(ep, __ATOMIC_RELAXED, __HIP_MEMORY_SCOPE_AGENT);
        unsigned prev = __hip_atomic_fetch_add(in, 1u, __ATOMIC_ACQ_REL, __HIP_MEMORY_SCOPE_AGENT);
        if (prev == nblk - 1u) {
            __hip_atomic_store(in, 0u, __ATOMIC_RELAXED, __HIP_MEMORY_SCOPE_AGENT);
            __hip_atomic_fetch_add(ep, 1u, __ATOMIC_ACQ_REL, __HIP_MEMORY_SCOPE_AGENT);
        } else {
            while (__hip_atomic_load(ep, __ATOMIC_ACQUIRE, __HIP_MEMORY_SCOPE_AGENT) == e)
                __builtin_amdgcn_s_sleep(8);
        }
    }
    __syncthreads();
}

// ---------------------------------------------------------- phase bodies ---
DEV void absmean_body(int bx, double* red,
    const float* __restrict__ WQ, const float* __restrict__ WK,
    const float* __restrict__ WV, const float* __restrict__ WO,
    double* __restrict__ part)
{
    int t = threadIdx.x;
    const float* W; int rel;
    if (bx < 64)       { W = WQ; rel = bx; }
    else if (bx < 96)  { W = WK; rel = bx - 64; }
    else if (bx < 128) { W = WV; rel = bx - 96; }
    else               { W = WO; rel = bx - 128; }
    size_t base = (size_t)rel * 16384;
    double acc = 0.0;
    for (int i = t; i < 16384; i += 256) acc += (double)fabsf(W[base + i]);
    red[t] = acc; __syncthreads();
    #pragma unroll
    for (int o = 128; o > 0; o >>= 1) {
        if (t < o) red[t] += red[t + o];
        __syncthreads();
    }
    if (t == 0) part[bx] = red[0];
}

DEV void act_row(const float* __restrict__ X, signed char* __restrict__ X8,
                 float* __restrict__ RS, int blk)
{
    int row = blk * 4 + (threadIdx.x >> 6);
    int lane = threadIdx.x & 63;
    const float4* xr = (const float4*)(X + (size_t)row * 1024) + lane * 4;
    float4 u[4];
    #pragma unroll
    for (int i = 0; i < 4; i++) u[i] = xr[i];
    float ss = 0.f, am = 0.f;
    #pragma unroll
    for (int i = 0; i < 4; i++) {
        ss += u[i].x * u[i].x + u[i].y * u[i].y + u[i].z * u[i].z + u[i].w * u[i].w;
        am = fmaxf(am, fmaxf(fmaxf(fabsf(u[i].x), fabsf(u[i].y)),
                             fmaxf(fabsf(u[i].z), fabsf(u[i].w))));
    }
    #pragma unroll
    for (int o = 32; o > 0; o >>= 1) {
        ss += __shfl_xor(ss, o);
        am = fmaxf(am, __shfl_xor(am, o));
    }
    float r = 1.f / sqrtf(ss * (1.f / 1024.f) + 1e-6f);
    float m = fmaxf(am * r, 1e-5f);
    float s = 127.f / m;
    int pk[4];
    #pragma unroll
    for (int i = 0; i < 4; i++) {
        int q0 = quant8((u[i].x * r) * s);
        int q1 = quant8((u[i].y * r) * s);
        int q2 = quant8((u[i].z * r) * s);
        int q3 = quant8((u[i].w * r) * s);
        pk[i] = (q0 & 0xff) | ((q1 & 0xff) << 8) | ((q2 & 0xff) << 16) | ((q3 & 0xff) << 24);
    }
    int4v pv = {pk[0], pk[1], pk[2], pk[3]};
    ((int4v*)(X8 + (size_t)row * 1024))[lane] = pv;
    if (lane == 0) RS[row] = m * (1.f / 127.f);
}

DEV void prep_body(int bx,
    const float* __restrict__ WQ, const float* __restrict__ WK,
    const float* __restrict__ WV, const float* __restrict__ WO,
    signed char* __restrict__ w8, const double* __restrict__ part,
    const float* __restrict__ X, signed char* __restrict__ X8, float* __restrict__ XS,
    const float* __restrict__ Y, signed char* __restrict__ Y8, float* __restrict__ YS)
{
    if (bx < 3072) {
        const float* W; signed char* O; int rel, wi;
        if (bx < 1024)      { W = WQ; O = w8;                           rel = bx;        wi = 0; }
        else if (bx < 1536) { W = WK; O = w8 + (1 << 20);               rel = bx - 1024; wi = 1; }
        else if (bx < 2048) { W = WV; O = w8 + (1 << 20) + (512 << 10); rel = bx - 1536; wi = 2; }
        else                { W = WO; O = w8 + (2 << 20);               rel = bx - 2048; wi = 3; }
        float inv = 1.f / beta_of(part, wi);
        int i = rel * 256 + threadIdx.x;
        float4 u = ((const float4*)W)[i];
        int q0 = tern1(u.x * inv);
        int q1 = tern1(u.y * inv);
        int q2 = tern1(u.z * inv);
        int q3 = tern1(u.w * inv);
        int packed = (q0 & 0xff) | ((q1 & 0xff) << 8) | ((q2 & 0xff) << 16) | ((q3 & 0xff) << 24);
        ((int*)O)[i] = packed;
    } else if (bx < 7168) {
        act_row(X, X8, XS, bx - 3072);     // 16384 rows
    } else {
        act_row(Y, Y8, YS, bx - 7168);     // 4096 rows
    }
}

// ------------------------------------------------------------------ GEMM ----
// 2-phase double-buffered K-loop (R3/R6 known-good structure).
DEV void gemm_core(
    signed char* As0, signed char* Bs0, signed char* As1, signed char* Bs1,
    const signed char* __restrict__ A, const signed char* __restrict__ B,
    float* __restrict__ outF, _Float16* __restrict__ outH,
    _Float16* __restrict__ outK, _Float16* __restrict__ outV,
    int N, int K,
    const float* __restrict__ rowscale, const double* __restrict__ part,
    int b0i, int b1i, int split, float extra, int mode,
    int bM, int bN)
{
    const int tid = threadIdx.x;
    const int lane = tid & 63, wid = tid >> 6;
    const int wr = wid >> 1, wc = wid & 1;
    const int lr = lane & 15, quad = lane >> 4;

    int4v zero = {0, 0, 0, 0};
    int4v acc[4][4];
    #pragma unroll
    for (int i = 0; i < 4; i++)
        #pragma unroll
        for (int j = 0; j < 4; j++) acc[i][j] = zero;

    const int srow = wid * 32 + (lane >> 2);
    const int soff = (lane & 3) * 16;
    const signed char* gA0 = A + (size_t)(bM * 128 + srow) * K + soff;
    const signed char* gA1 = gA0 + (size_t)16 * K;
    const signed char* gB0 = B + (size_t)(bN * 128 + srow) * K + soff;
    const signed char* gB1 = gB0 + (size_t)16 * K;
    const int lo0 = wid * 2048, lo1 = wid * 2048 + 1024;

    // prologue: stage k-tile 0 into buffer 0; betas overlap the staging
    gl2lds16(gA0, As0 + lo0);
    gl2lds16(gA1, As0 + lo1);
    gl2lds16(gB0, Bs0 + lo0);
    gl2lds16(gB1, Bs0 + lo1);
    const float s0 = beta_of(part, b0i) * extra;
    const float s1 = (b1i == b0i) ? s0 : beta_of(part, b1i) * extra;
    __syncthreads();

#define GEMM_COMPUTE(AS, BS)                                                   \
    {                                                                          \
        int4v af[4], bfr[4];                                                   \
        _Pragma("unroll")                                                      \
        for (int tm = 0; tm < 4; tm++)                                         \
            af[tm] = *(const int4v*)((AS) + (wr * 64 + tm * 16 + lr) * 64 + quad * 16); \
        _Pragma("unroll")                                                      \
        for (int tn = 0; tn < 4; tn++)                                         \
            bfr[tn] = *(const int4v*)((BS) + (wc * 64 + tn * 16 + lr) * 64 + quad * 16); \
        _Pragma("unroll")                                                      \
        for (int tm = 0; tm < 4; tm++)                                         \
            _Pragma("unroll")                                                  \
            for (int tn = 0; tn < 4; tn++)                                     \
                acc[tm][tn] = __builtin_amdgcn_mfma_i32_16x16x64_i8(af[tm], bfr[tn], acc[tm][tn], 0, 0, 0); \
    }

    for (int kb = 0; kb < K; kb += 128) {
        if (kb + 64 < K) {
            gl2lds16(gA0 + kb + 64, As1 + lo0);
            gl2lds16(gA1 + kb + 64, As1 + lo1);
            gl2lds16(gB0 + kb + 64, Bs1 + lo0);
            gl2lds16(gB1 + kb + 64, Bs1 + lo1);
        }
        GEMM_COMPUTE(As0, Bs0);
        __syncthreads();
        if (kb + 128 < K) {
            gl2lds16(gA0 + kb + 128, As0 + lo0);
            gl2lds16(gA1 + kb + 128, As0 + lo1);
            gl2lds16(gB0 + kb + 128, Bs0 + lo0);
            gl2lds16(gB1 + kb + 128, Bs0 + lo1);
        }
        GEMM_COMPUTE(As1, Bs1);
        __syncthreads();
    }
#undef GEMM_COMPUTE

    #pragma unroll
    for (int tm = 0; tm < 4; tm++) {
        #pragma unroll
        for (int r = 0; r < 4; r++) {
            int grow = bM * 128 + wr * 64 + tm * 16 + quad * 4 + r;
            float rs = rowscale[grow];
            #pragma unroll
            for (int tn = 0; tn < 4; tn++) {
                int col = bN * 128 + wc * 64 + tn * 16 + lr;
                float v = (float)acc[tm][tn][r] * rs * (col < split ? s0 : s1);
                if (mode == 0) {
                    outF[(size_t)grow * N + col] = v;
                } else if (mode == 1) {
                    outH[(size_t)grow * 1024 + col] = (_Float16)v;
                } else {
                    if (col < 512)
                        outK[(size_t)grow * 512 + col] = (_Float16)v;
                    else
                        outV[((size_t)(grow >> 8) * 512 + (col - 512)) * 256 + (grow & 255)] = (_Float16)v;
                }
            }
        }
    }
}

// -------------------------------------------------------------- attention ---
DEV void attn_body(int bx, const _Float16* Qh, const _Float16* __restrict__ Kh,
                   const _Float16* __restrict__ Vt, _Float16* Oh, _Float16* KVs)
{
    const int tid = threadIdx.x;
    const int lane = tid & 63;
    const int w = tid >> 6;
    const int lq = lane & 15;
    const int quad = lane >> 4;
    const int swz = (lq & 7) << 4;

    const int nt = bx & 15, g = (bx >> 4) & 1, h = (bx >> 5) & 7, b = bx >> 8;
    const int rbase = b * 1024 + nt * 64 + w * 16;
    const int qcol0 = (h * 2 + g) * 64;

    __syncthreads();   // protect LDS reuse across grid-stride iterations

    half8 aq[2];
    #pragma unroll
    for (int ks = 0; ks < 2; ks++)
        aq[ks] = *(const half8*)(Qh + (size_t)(rbase + lq) * 1024 + qcol0 + ks * 32 + quad * 8);

    // stage K tile: permuted slot rows + XOR bank swizzle
    {
        int kb = tid >> 3;
        int c  = tid & 7;
        int rp = (kb & 3) | ((kb >> 1) & 12) | ((kb & 4) << 2);
        const _Float16* kg = Kh + (size_t)(b * 256 + kb) * 512 + h * 64 + c * 8;
        char* lb = (char*)KVs;
        #pragma unroll
        for (int j = 0; j < 8; j++) {
            int row = 32 * j + rp;
            int off = (row * 128 + c * 16) ^ ((row & 7) << 4);
            *(half8*)(lb + off) = *(const half8*)(kg + (size_t)32 * j * 512);
        }
    }
    __syncthreads();

    float4v acc[16];
    float4v zf = {0.f, 0.f, 0.f, 0.f};
    #pragma unroll
    for (int t = 0; t < 16; t++) acc[t] = zf;
    const int kc0 = (quad * 16) ^ swz;
    const int kc1 = (64 + quad * 16) ^ swz;
    __builtin_amdgcn_s_setprio(1);
    #pragma unroll
    for (int t = 0; t < 16; t++) {
        const char* krow = (const char*)KVs + (t * 16 + lq) * 128;
        half8 kf0 = *(const half8*)(krow + kc0);
        acc[t] = __builtin_amdgcn_mfma_f32_16x16x32_f16(kf0, aq[0], acc[t], 0, 0, 0);
        half8 kf1 = *(const half8*)(krow + kc1);
        acc[t] = __builtin_amdgcn_mfma_f32_16x16x32_f16(kf1, aq[1], acc[t], 0, 0, 0);
    }
    __builtin_amdgcn_s_setprio(0);

    float m = acc[0][0];
    #pragma unroll
    for (int t = 0; t < 16; t++) {
        #pragma unroll
        for (int r = 0; r < 4; r++) m = fmaxf(m, acc[t][r]);
    }
    m = fmaxf(m, __shfl_xor(m, 16));
    m = fmaxf(m, __shfl_xor(m, 32));
    float l = 0.f;
    #pragma unroll
    for (int t = 0; t < 16; t++) {
        #pragma unroll
        for (int r = 0; r < 4; r++) {
            float p = __expf(acc[t][r] - m);
            acc[t][r] = p;
            l += p;
        }
    }
    l += __shfl_xor(l, 16);
    l += __shfl_xor(l, 32);

    __syncthreads();

    // stage V^T tile, XOR-swizzled, overlays K
    {
        int row = tid >> 5, c = tid & 31;
        const _Float16* vg = Vt + ((size_t)b * 512 + h * 64 + row) * 256 + c * 8;
        char* lb = (char*)KVs;
        #pragma unroll
        for (int j = 0; j < 8; j++) {
            int rr = row + 8 * j;
            int off = (rr * 512 + c * 16) ^ ((rr & 7) << 4);
            *(half8*)(lb + off) = *(const half8*)(vg + (size_t)8 * j * 256);
        }
    }
    __syncthreads();

    float4v oacc[4];
    #pragma unroll
    for (int dt = 0; dt < 4; dt++) oacc[dt] = zf;
    __builtin_amdgcn_s_setprio(1);
    #pragma unroll
    for (int ks = 0; ks < 8; ks++) {
        half8 pf;
        #pragma unroll
        for (int r = 0; r < 4; r++) {
            pf[r]     = (_Float16)acc[2 * ks][r];
            pf[4 + r] = (_Float16)acc[2 * ks + 1][r];
        }
        const int vc = (ks * 64 + quad * 16) ^ swz;
        #pragma unroll
        for (int dt = 0; dt < 4; dt++) {
            half8 bv = *(const half8*)((const char*)KVs + (dt * 16 + lq) * 512 + vc);
            oacc[dt] = __builtin_amdgcn_mfma_f32_16x16x32_f16(pf, bv, oacc[dt], 0, 0, 0);
        }
    }
    __builtin_amdgcn_s_setprio(0);

    float linv = 1.f / l;
    float invr[4];
    #pragma unroll
    for (int r = 0; r < 4; r++) invr[r] = __shfl(linv, quad * 4 + r);
    #pragma unroll
    for (int dt = 0; dt < 4; dt++) {
        #pragma unroll
        for (int r = 0; r < 4; r++) {
            Oh[(size_t)(rbase + quad * 4 + r) * 1024 + qcol0 + dt * 16 + lq] =
                (_Float16)(oacc[dt][r] * invr[r]);
        }
    }
}

// ---------------------------------------------------- LayerNorm + re-quant ---
DEV void ln_body(int v, const _Float16* __restrict__ AO, const float* __restrict__ G,
                 const float* __restrict__ Bt, signed char* __restrict__ O8,
                 float* __restrict__ OS)
{
    int row = v * 4 + (threadIdx.x >> 6);
    int lane = threadIdx.x & 63;
    const _Float16* xr = AO + (size_t)row * 1024 + lane * 16;
    half8 h0 = *(const half8*)xr;
    half8 h1 = *(const half8*)(xr + 8);
    float x[16];
    #pragma unroll
    for (int i = 0; i < 8; i++) { x[i] = (float)h0[i]; x[8 + i] = (float)h1[i]; }
    float sx = 0.f, sx2 = 0.f;
    #pragma unroll
    for (int i = 0; i < 16; i++) { sx += x[i]; sx2 += x[i] * x[i]; }
    #pragma unroll
    for (int o = 32; o > 0; o >>= 1) {
        sx += __shfl_xor(sx, o);
        sx2 += __shfl_xor(sx2, o);
    }
    float mu = sx * (1.f / 1024.f);
    float var = sx2 * (1.f / 1024.f) - mu * mu;
    float rstd = 1.f / sqrtf(var + 1e-5f);

    const float4* gp = (const float4*)(G + lane * 16);
    const float4* bp = (const float4*)(Bt + lane * 16);
    float l[16];
    #pragma unroll
    for (int i = 0; i < 4; i++) {
        float4 gv = gp[i], bv = bp[i];
        l[i * 4 + 0] = (x[i * 4 + 0] - mu) * rstd * gv.x + bv.x;
        l[i * 4 + 1] = (x[i * 4 + 1] - mu) * rstd * gv.y + bv.y;
        l[i * 4 + 2] = (x[i * 4 + 2] - mu) * rstd * gv.z + bv.z;
        l[i * 4 + 3] = (x[i * 4 + 3] - mu) * rstd * gv.w + bv.w;
    }
    float msq = 0.f, am = 0.f;
    #pragma unroll
    for (int i = 0; i < 16; i++) { msq += l[i] * l[i]; am = fmaxf(am, fabsf(l[i])); }
    #pragma unroll
    for (int o = 32; o > 0; o >>= 1) {
        msq += __shfl_xor(msq, o);
        am = fmaxf(am, __shfl_xor(am, o));
    }
    float r2 = 1.f / sqrtf(msq * (1.f / 1024.f) + 1e-6f);
    float mx = fmaxf(am * r2, 1e-5f);
    float s = 127.f / mx;
    int pk[4];
    #pragma unroll
    for (int i = 0; i < 4; i++) {
        int q0 = quant8((l[i * 4 + 0] * r2) * s);
        int q1 = quant8((l[i * 4 + 1] * r2) * s);
        int q2 = quant8((l[i * 4 + 2] * r2) * s);
        int q3 = quant8((l[i * 4 + 3] * r2) * s);
        pk[i] = (q0 & 0xff) | ((q1 & 0xff) << 8) | ((q2 & 0xff) << 16) | ((q3 & 0xff) << 24);
    }
    int4v pv = {pk[0], pk[1], pk[2], pk[3]};
    ((int4v*)(O8 + (size_t)row * 1024))[lane] = pv;
    if (lane == 0) OS[row] = mx * (1.f / 127.f);
}

// --------------------------------------------------------------- mega 1 ----
// absmean -> bar -> prep(wquant+actX+actY, grid-stride) -> bar -> proj.
// Per-XCD proj map: XCD x owns q-tiles x*128..x*128+127 (contiguous bM =>
// 2MB A-chunk + 1MB B in its L2) and kv-tiles x*32..x*32+31 (tail runs on
// blocks 0..255 = 1 per CU across ALL XCDs).
__global__ __launch_bounds__(256, 4) void mega1(
    const float* __restrict__ WQ, const float* __restrict__ WK,
    const float* __restrict__ WV, const float* __restrict__ WO,
    double* __restrict__ part, signed char* __restrict__ w8,
    const float* __restrict__ X, signed char* __restrict__ x8, float* __restrict__ xs,
    const float* __restrict__ Y, signed char* __restrict__ y8, float* __restrict__ ys,
    _Float16* __restrict__ qf16, _Float16* __restrict__ kf16,
    _Float16* __restrict__ vt16, unsigned* bars)
{
    __shared__ __align__(16) signed char SM[32768];
    const int b = blockIdx.x;          // 0..1023

    if (b < 192) absmean_body(b, (double*)SM, WQ, WK, WV, WO, part);
    gridbar(bars + 0, bars + 1, 1024);

    #pragma unroll 1
    for (int v = b; v < 8192; v += 1024)
        prep_body(v, WQ, WK, WV, WO, w8, part, X, x8, xs, Y, y8, ys);
    gridbar(bars + 2, bars + 3, 1024);

    signed char* As0 = SM;
    signed char* Bs0 = SM + 8192;
    signed char* As1 = SM + 16384;
    signed char* Bs1 = SM + 24576;
    const signed char* wq8 = w8;
    const signed char* kv8 = w8 + (1 << 20);
    const int x = b & 7, s = b >> 3;
    {
        int qi = x * 128 + s;
        gemm_core(As0, Bs0, As1, Bs1, x8, wq8, nullptr, qf16, nullptr, nullptr,
                  1024, 1024, xs, part, 0, 0, 1024, 0.125f, 1, qi >> 3, qi & 7);
    }
    if (s < 32) {
        int ki = x * 32 + s;
        gemm_core(As0, Bs0, As1, Bs1, y8, kv8, nullptr, nullptr, kf16, vt16,
                  1024, 1024, ys, part, 1, 2, 512, 1.f, 2, ki >> 3, ki & 7);
    }
}

// --------------------------------------------------------------- mega 2 ----
// attn x4 (disjoint tiles) -> bar -> ln x4 -> bar -> out-GEMM (1 tile/blk).
__global__ __launch_bounds__(256, 4) void mega2(
    _Float16* qf16, const _Float16* __restrict__ kf16,
    const _Float16* __restrict__ vt16,
    const float* __restrict__ G, const float* __restrict__ Bt,
    signed char* __restrict__ o8, float* __restrict__ os,
    const signed char* __restrict__ wo8, float* __restrict__ outF,
    const double* __restrict__ part, unsigned* bars)
{
    __shared__ __align__(16) signed char SM[32768];
    const int b = blockIdx.x;          // 0..1023

    #pragma unroll 1
    for (int v = b; v < 4096; v += 1024)
        attn_body(v, qf16, kf16, vt16, qf16, (_Float16*)SM);
    gridbar(bars + 4, bars + 5, 1024);

    #pragma unroll 1
    for (int v = b; v < 4096; v += 1024)
        ln_body(v, qf16, G, Bt, o8, os);
    gridbar(bars + 6, bars + 7, 1024);

    signed char* As0 = SM;
    signed char* Bs0 = SM + 8192;
    signed char* As1 = SM + 16384;
    signed char* Bs1 = SM + 24576;
    const int f2 = (b & 7) * 128 + (b >> 3);
    gemm_core(As0, Bs0, As1, Bs1, o8, wo8, outF, nullptr, nullptr, nullptr,
              1024, 1024, os, part, 3, 3, 1024, 1.f, 0, f2 >> 3, f2 & 7);
}

// ------------------------------------------------------------------ launch ---
extern "C" void kernel_launch(void* const* d_in, const int* in_sizes, int n_in,
                              void* d_out, int out_size, void* d_ws, size_t ws_size,
                              hipStream_t stream)
{
    const float* X  = (const float*)d_in[0];
    const float* Y  = (const float*)d_in[1];
    const float* WQ = (const float*)d_in[2];
    const float* WK = (const float*)d_in[3];
    const float* WV = (const float*)d_in[4];
    const float* WO = (const float*)d_in[5];
    const float* G  = (const float*)d_in[6];
    const float* Bt = (const float*)d_in[7];

    // workspace layout (~64 MB)
    char* ws = (char*)d_ws;
    unsigned* bars = (unsigned*)ws;                    // 64 B (barrier state)
    double* part  = (double*)(ws + 256);               // 1536 B
    char* w8  = ws + 4096;                             // 3 MB (wq | wk+wv | wo)
    char* x8  = w8 + (3 << 20);                        // 16 MB (reused as o8)
    char* y8  = x8 + (16 << 20);                       // 4 MB
    float* xs = (float*)(y8 + (4 << 20));              // 64 KB
    float* ys = xs + 16384;                            // 16 KB
    float* os = ys + 4096;                             // 64 KB
    _Float16* qf16 = (_Float16*)(os + 16384);          // 32 MB (attn in-place)
    _Float16* kf16 = qf16 + (size_t)16384 * 1024;      // 4 MB
    _Float16* vt16 = kf16 + (size_t)4096 * 512;        // 4 MB
    char* o8  = x8;

    hipMemsetAsync(d_ws, 0, 64, stream);               // barrier state init

    mega1<<<1024, 256, 0, stream>>>(
        WQ, WK, WV, WO, part, (signed char*)w8,
        X, (signed char*)x8, xs, Y, (signed char*)y8, ys,
        qf16, kf16, vt16, bars);

    mega2<<<1024, 256, 0, stream>>>(
        qf16, kf16, vt16, G, Bt, (signed char*)o8, os,
        (signed char*)(w8 + (2 << 20)), (float*)d_out, part, bars);
}

// Round 9
// 319.794 us; speedup vs baseline: 4.6166x; 4.6166x over previous
//
#include <hip/hip_runtime.h>
#include <hip/hip_bf16.h>

typedef int int4v __attribute__((ext_vector_type(4)));
typedef float float4v __attribute__((ext_vector_type(4)));
typedef _Float16 half8 __attribute__((ext_vector_type(8)));

#define DEV __device__ __forceinline__

DEV signed char quant8(float v) {
    int q = (int)rintf(v);
    q = q < -128 ? -128 : (q > 127 ? 127 : q);
    return (signed char)q;
}

DEV int tern1(float v) {
    int q = (int)rintf(v);
    q = q < -1 ? -1 : (q > 1 ? 1 : q);
    return q;
}

// async global->LDS, 16B per lane; LDS dest = wave-uniform base + lane*16
DEV void gl2lds16(const void* g, void* l) {
    __builtin_amdgcn_global_load_lds(
        (const __attribute__((address_space(1))) void*)g,
        (__attribute__((address_space(3))) void*)l, 16, 0, 0);
}

// wave-redundant absmean beta from the partial sums (no betas kernel)
DEV float beta_of(const double* __restrict__ part, int wi) {
    int offs = wi == 0 ? 0 : (wi == 1 ? 64 : (wi == 2 ? 96 : 128));
    int cnt  = (wi == 1 || wi == 2) ? 32 : 64;
    double invc = (wi == 1 || wi == 2) ? (1.0 / 524288.0) : (1.0 / 1048576.0);
    int lane = threadIdx.x & 63;
    double v = (lane < cnt) ? part[offs + lane] : 0.0;
    #pragma unroll
    for (int o = 32; o > 0; o >>= 1) v += __shfl_down(v, o);
    v = __shfl(v, 0);
    return fmaxf((float)(v * invc), 1e-5f);
}

// ---------------------------------------------------------------- weights ---
__global__ __launch_bounds__(256) void absmean_all(
    const float* __restrict__ WQ, const float* __restrict__ WK,
    const float* __restrict__ WV, const float* __restrict__ WO,
    double* __restrict__ part)
{
    __shared__ double red[256];
    int bx = blockIdx.x, t = threadIdx.x;
    const float* W; int rel;
    if (bx < 64)       { W = WQ; rel = bx; }
    else if (bx < 96)  { W = WK; rel = bx - 64; }
    else if (bx < 128) { W = WV; rel = bx - 96; }
    else               { W = WO; rel = bx - 128; }
    size_t base = (size_t)rel * 16384;
    double acc = 0.0;
    for (int i = t; i < 16384; i += 256) acc += (double)fabsf(W[base + i]);
    red[t] = acc; __syncthreads();
    #pragma unroll
    for (int o = 128; o > 0; o >>= 1) {
        if (t < o) red[t] += red[t + o];
        __syncthreads();
    }
    if (t == 0) part[bx] = red[0];
}

// --------------------------------------------- fused wquant + act_quant -----
DEV void act_row(const float* __restrict__ X, signed char* __restrict__ X8,
                 float* __restrict__ RS, int blk)
{
    int row = blk * 4 + (threadIdx.x >> 6);
    int lane = threadIdx.x & 63;
    const float4* xr = (const float4*)(X + (size_t)row * 1024) + lane * 4;
    float4 u[4];
    #pragma unroll
    for (int i = 0; i < 4; i++) u[i] = xr[i];
    float ss = 0.f, am = 0.f;
    #pragma unroll
    for (int i = 0; i < 4; i++) {
        ss += u[i].x * u[i].x + u[i].y * u[i].y + u[i].z * u[i].z + u[i].w * u[i].w;
        am = fmaxf(am, fmaxf(fmaxf(fabsf(u[i].x), fabsf(u[i].y)),
                             fmaxf(fabsf(u[i].z), fabsf(u[i].w))));
    }
    #pragma unroll
    for (int o = 32; o > 0; o >>= 1) {
        ss += __shfl_xor(ss, o);
        am = fmaxf(am, __shfl_xor(am, o));
    }
    float r = 1.f / sqrtf(ss * (1.f / 1024.f) + 1e-6f);
    float m = fmaxf(am * r, 1e-5f);
    float s = 127.f / m;
    int pk[4];
    #pragma unroll
    for (int i = 0; i < 4; i++) {
        int q0 = quant8((u[i].x * r) * s);
        int q1 = quant8((u[i].y * r) * s);
        int q2 = quant8((u[i].z * r) * s);
        int q3 = quant8((u[i].w * r) * s);
        pk[i] = (q0 & 0xff) | ((q1 & 0xff) << 8) | ((q2 & 0xff) << 16) | ((q3 & 0xff) << 24);
    }
    int4v pv = {pk[0], pk[1], pk[2], pk[3]};
    ((int4v*)(X8 + (size_t)row * 1024))[lane] = pv;
    if (lane == 0) RS[row] = m * (1.f / 127.f);
}

__global__ __launch_bounds__(256) void prep_all(
    const float* __restrict__ WQ, const float* __restrict__ WK,
    const float* __restrict__ WV, const float* __restrict__ WO,
    signed char* __restrict__ w8, const double* __restrict__ part,
    const float* __restrict__ X, signed char* __restrict__ X8, float* __restrict__ XS,
    const float* __restrict__ Y, signed char* __restrict__ Y8, float* __restrict__ YS)
{
    int bx = blockIdx.x;
    if (bx < 3072) {
        // ---- ternary weight quant (needs part[] from absmean)
        const float* W; signed char* O; int rel, wi;
        if (bx < 1024)      { W = WQ; O = w8;                           rel = bx;        wi = 0; }
        else if (bx < 1536) { W = WK; O = w8 + (1 << 20);               rel = bx - 1024; wi = 1; }
        else if (bx < 2048) { W = WV; O = w8 + (1 << 20) + (512 << 10); rel = bx - 1536; wi = 2; }
        else                { W = WO; O = w8 + (2 << 20);               rel = bx - 2048; wi = 3; }
        float inv = 1.f / beta_of(part, wi);
        int i = rel * 256 + threadIdx.x;
        float4 u = ((const float4*)W)[i];
        int q0 = tern1(u.x * inv);
        int q1 = tern1(u.y * inv);
        int q2 = tern1(u.z * inv);
        int q3 = tern1(u.w * inv);
        int packed = (q0 & 0xff) | ((q1 & 0xff) << 8) | ((q2 & 0xff) << 16) | ((q3 & 0xff) << 24);
        ((int*)O)[i] = packed;
    } else if (bx < 7168) {
        act_row(X, X8, XS, bx - 3072);     // 16384 rows
    } else {
        act_row(Y, Y8, YS, bx - 7168);     // 4096 rows
    }
}

// ------------------------------------------------------------------ GEMM ----
// C[M,N] = A[M,K](int8) . B[N,K](int8 ternary)^T, dequant rowscale*beta.
// 2-phase double-buffered K-loop (R3 known-good): stage(t+1) via
// global_load_lds before compute(t); ONE __syncthreads per K-step (its
// vmcnt(0) drain lands after the MFMAs). Betas computed in the prologue so
// their latency hides under the first staging barrier. mode is compile-time
// at each call site (dead branches eliminated).
DEV void gemm_core(
    signed char* As0, signed char* Bs0, signed char* As1, signed char* Bs1,
    const signed char* __restrict__ A, const signed char* __restrict__ B,
    float* __restrict__ outF, _Float16* __restrict__ outH,
    _Float16* __restrict__ outK, _Float16* __restrict__ outV,
    int N, int K,
    const float* __restrict__ rowscale, const double* __restrict__ part,
    int b0i, int b1i, int split, float extra, int mode,
    int bM, int bN)
{
    const int tid = threadIdx.x;
    const int lane = tid & 63, wid = tid >> 6;
    const int wr = wid >> 1, wc = wid & 1;
    const int lr = lane & 15, quad = lane >> 4;

    int4v zero = {0, 0, 0, 0};
    int4v acc[4][4];
    #pragma unroll
    for (int i = 0; i < 4; i++)
        #pragma unroll
        for (int j = 0; j < 4; j++) acc[i][j] = zero;

    const int srow = wid * 32 + (lane >> 2);
    const int soff = (lane & 3) * 16;
    const signed char* gA0 = A + (size_t)(bM * 128 + srow) * K + soff;
    const signed char* gA1 = gA0 + (size_t)16 * K;
    const signed char* gB0 = B + (size_t)(bN * 128 + srow) * K + soff;
    const signed char* gB1 = gB0 + (size_t)16 * K;
    const int lo0 = wid * 2048, lo1 = wid * 2048 + 1024;

    // prologue: stage k-tile 0 into buffer 0; betas overlap the staging
    gl2lds16(gA0, As0 + lo0);
    gl2lds16(gA1, As0 + lo1);
    gl2lds16(gB0, Bs0 + lo0);
    gl2lds16(gB1, Bs0 + lo1);
    const float s0 = beta_of(part, b0i) * extra;
    const float s1 = (b1i == b0i) ? s0 : beta_of(part, b1i) * extra;
    __syncthreads();

#define GEMM_COMPUTE(AS, BS)                                                   \
    {                                                                          \
        int4v af[4], bfr[4];                                                   \
        _Pragma("unroll")                                                      \
        for (int tm = 0; tm < 4; tm++)                                         \
            af[tm] = *(const int4v*)((AS) + (wr * 64 + tm * 16 + lr) * 64 + quad * 16); \
        _Pragma("unroll")                                                      \
        for (int tn = 0; tn < 4; tn++)                                         \
            bfr[tn] = *(const int4v*)((BS) + (wc * 64 + tn * 16 + lr) * 64 + quad * 16); \
        _Pragma("unroll")                                                      \
        for (int tm = 0; tm < 4; tm++)                                         \
            _Pragma("unroll")                                                  \
            for (int tn = 0; tn < 4; tn++)                                     \
                acc[tm][tn] = __builtin_amdgcn_mfma_i32_16x16x64_i8(af[tm], bfr[tn], acc[tm][tn], 0, 0, 0); \
    }

    for (int kb = 0; kb < K; kb += 128) {
        if (kb + 64 < K) {
            gl2lds16(gA0 + kb + 64, As1 + lo0);
            gl2lds16(gA1 + kb + 64, As1 + lo1);
            gl2lds16(gB0 + kb + 64, Bs1 + lo0);
            gl2lds16(gB1 + kb + 64, Bs1 + lo1);
        }
        GEMM_COMPUTE(As0, Bs0);
        __syncthreads();
        if (kb + 128 < K) {
            gl2lds16(gA0 + kb + 128, As0 + lo0);
            gl2lds16(gA1 + kb + 128, As0 + lo1);
            gl2lds16(gB0 + kb + 128, Bs0 + lo0);
            gl2lds16(gB1 + kb + 128, Bs0 + lo1);
        }
        GEMM_COMPUTE(As1, Bs1);
        __syncthreads();
    }
#undef GEMM_COMPUTE

    #pragma unroll
    for (int tm = 0; tm < 4; tm++) {
        #pragma unroll
        for (int r = 0; r < 4; r++) {
            int grow = bM * 128 + wr * 64 + tm * 16 + quad * 4 + r;
            float rs = rowscale[grow];
            #pragma unroll
            for (int tn = 0; tn < 4; tn++) {
                int col = bN * 128 + wc * 64 + tn * 16 + lr;
                float v = (float)acc[tm][tn][r] * rs * (col < split ? s0 : s1);
                if (mode == 0) {
                    outF[(size_t)grow * N + col] = v;
                } else if (mode == 1) {
                    outH[(size_t)grow * 1024 + col] = (_Float16)v;
                } else {
                    if (col < 512)
                        outK[(size_t)grow * 512 + col] = (_Float16)v;
                    else
                        outV[((size_t)(grow >> 8) * 512 + (col - 512)) * 256 + (grow & 255)] = (_Float16)v;
                }
            }
        }
    }
}

// fused q-projection (mode 1) + k/v-projection (mode 2) in one launch.
// BALANCED per-XCD map (fixes R7's imbalance): block b -> XCD x=b&7,
// slot s=b>>3 (0..159). s<128 -> q-tile x*128+s (contiguous bM => 2MB
// A-chunk + 1MB B in that XCD's L2); s>=128 -> kv-tile x*32+(s-128).
// Every XCD gets 128 q + 32 kv; the scatter epilogue spreads evenly.
// launch_bounds(256,5): 1280 blocks = exactly 5 blocks/CU (5 x 32KB =
// 160KB LDS, VGPR cap 102 >= measured 80) -> whole grid co-resident,
// no second dispatch wave.
__global__ __launch_bounds__(256, 5) void proj_fused(
    const signed char* __restrict__ x8, const signed char* __restrict__ wq8,
    const signed char* __restrict__ y8, const signed char* __restrict__ kv8,
    _Float16* __restrict__ qf16, _Float16* __restrict__ kf16,
    _Float16* __restrict__ vt16,
    const float* __restrict__ xs, const float* __restrict__ ys,
    const double* __restrict__ part)
{
    __shared__ __align__(16) signed char As0[128 * 64];
    __shared__ __align__(16) signed char Bs0[128 * 64];
    __shared__ __align__(16) signed char As1[128 * 64];
    __shared__ __align__(16) signed char Bs1[128 * 64];
    const int b = blockIdx.x;
    const int x = b & 7, s = b >> 3;
    if (s < 128) {
        int qi = x * 128 + s;
        gemm_core(As0, Bs0, As1, Bs1, x8, wq8, nullptr, qf16, nullptr, nullptr,
                  1024, 1024, xs, part, 0, 0, 1024, 0.125f, 1, qi >> 3, qi & 7);
    } else {
        int ki = x * 32 + (s - 128);
        gemm_core(As0, Bs0, As1, Bs1, y8, kv8, nullptr, nullptr, kf16, vt16,
                  1024, 1024, ys, part, 1, 2, 512, 1.f, 2, ki >> 3, ki & 7);
    }
}

// out projection (mode 0) -> f32
__global__ __launch_bounds__(256) void gemm_out(
    const signed char* __restrict__ A, const signed char* __restrict__ B,
    float* __restrict__ outF,
    const float* __restrict__ rowscale, const double* __restrict__ part)
{
    __shared__ __align__(16) signed char As0[128 * 64];
    __shared__ __align__(16) signed char Bs0[128 * 64];
    __shared__ __align__(16) signed char As1[128 * 64];
    __shared__ __align__(16) signed char Bs1[128 * 64];
    const int flat = blockIdx.y * 8 + blockIdx.x;
    const int chunk = (gridDim.x * gridDim.y) >> 3;
    const int f2 = (flat & 7) * chunk + (flat >> 3);
    gemm_core(As0, Bs0, As1, Bs1, A, B, outF, nullptr, nullptr, nullptr,
              1024, 1024, rowscale, part, 3, 3, 1024, 1.f, 0, f2 >> 3, f2 & 7);
}

// -------------------------------------------------------------- attention ---
// MFMA GQA, swapped-operand QK^T. Wave = 16 query rows of one (b,h,g).
// K tile staged with KEY-PERMUTED slot rows + XOR bank swizzle into a 32 KB
// region; V^T overlays the same region after QK^T. Swapped mfma(K,Q) puts a
// full 64-key slice of query q=lane&15 in-lane, so softmax is in-lane + 2
// shuffles, and the key permutation row(k)=(k&~31)|((k&4)<<2)|((k>>1)&12)|(k&3)
// makes the S^T C-layout coincide with PV's A-fragment layout: P is built by
// pure in-lane f32->f16 packing. No P LDS, no cross-lane P traffic.
// T5: setprio(1) around MFMA clusters.
__global__ __launch_bounds__(256, 4) void attn_mfma(
    const _Float16* Qh, const _Float16* __restrict__ Kh,
    const _Float16* __restrict__ Vt, _Float16* Oh)
{
    __shared__ __align__(16) _Float16 KVs[256 * 64];   // 32768 B; K then V^T overlay

    const int tid = threadIdx.x;
    const int lane = tid & 63;
    const int w = tid >> 6;
    const int lq = lane & 15;
    const int quad = lane >> 4;
    const int swz = (lq & 7) << 4;           // XOR bank swizzle (bytes)

    const int bx = blockIdx.x;               // b(16) x h(8) x g(2) x nt(16)
    const int nt = bx & 15, g = (bx >> 4) & 1, h = (bx >> 5) & 7, b = bx >> 8;
    const int rbase = b * 1024 + nt * 64 + w * 16;
    const int qcol0 = (h * 2 + g) * 64;

    // Q fragments (B-operand under swap), 1/8 scale folded in q-gemm epilogue
    half8 aq[2];
    #pragma unroll
    for (int ks = 0; ks < 2; ks++)
        aq[ks] = *(const half8*)(Qh + (size_t)(rbase + lq) * 1024 + qcol0 + ks * 32 + quad * 8);

    // ---- stage K tile: key kap -> permuted slot row, XOR-swizzled 16B chunks
    {
        int kb = tid >> 3;                   // kap & 31
        int c  = tid & 7;
        int rp = (kb & 3) | ((kb >> 1) & 12) | ((kb & 4) << 2);  // perm of 5 LSBs
        const _Float16* kg = Kh + (size_t)(b * 256 + kb) * 512 + h * 64 + c * 8;
        char* lb = (char*)KVs;
        #pragma unroll
        for (int j = 0; j < 8; j++) {
            int row = 32 * j + rp;
            int off = (row * 128 + c * 16) ^ ((row & 7) << 4);
            *(half8*)(lb + off) = *(const half8*)(kg + (size_t)32 * j * 512);
        }
    }
    __syncthreads();

    // ---- QK^T (swapped): acc[t] = mfma(Kfrag, Qfrag) -> S^T, lane holds
    // scores of query q=lq at keys (t>>1)*32 + quad*8 + (t&1)*4 + r
    float4v acc[16];
    float4v zf = {0.f, 0.f, 0.f, 0.f};
    #pragma unroll
    for (int t = 0; t < 16; t++) acc[t] = zf;
    const int kc0 = (quad * 16) ^ swz;
    const int kc1 = (64 + quad * 16) ^ swz;
    __builtin_amdgcn_s_setprio(1);
    #pragma unroll
    for (int t = 0; t < 16; t++) {
        const char* krow = (const char*)KVs + (t * 16 + lq) * 128;
        half8 kf0 = *(const half8*)(krow + kc0);
        acc[t] = __builtin_amdgcn_mfma_f32_16x16x32_f16(kf0, aq[0], acc[t], 0, 0, 0);
        half8 kf1 = *(const half8*)(krow + kc1);
        acc[t] = __builtin_amdgcn_mfma_f32_16x16x32_f16(kf1, aq[1], acc[t], 0, 0, 0);
    }
    __builtin_amdgcn_s_setprio(0);

    // ---- softmax for q=lq: in-lane over 64 keys + cross-quad combine
    float m = acc[0][0];
    #pragma unroll
    for (int t = 0; t < 16; t++) {
        #pragma unroll
        for (int r = 0; r < 4; r++) m = fmaxf(m, acc[t][r]);
    }
    m = fmaxf(m, __shfl_xor(m, 16));
    m = fmaxf(m, __shfl_xor(m, 32));
    float l = 0.f;
    #pragma unroll
    for (int t = 0; t < 16; t++) {
        #pragma unroll
        for (int r = 0; r < 4; r++) {
            float p = __expf(acc[t][r] - m);
            acc[t][r] = p;
            l += p;
        }
    }
    l += __shfl_xor(l, 16);
    l += __shfl_xor(l, 32);

    __syncthreads();   // all waves done reading K region

    // ---- stage V^T tile (64 x 256 f16), XOR-swizzled rows, overlays K
    {
        int row = tid >> 5, c = tid & 31;
        const _Float16* vg = Vt + ((size_t)b * 512 + h * 64 + row) * 256 + c * 8;
        char* lb = (char*)KVs;
        #pragma unroll
        for (int j = 0; j < 8; j++) {
            int rr = row + 8 * j;
            int off = (rr * 512 + c * 16) ^ ((rr & 7) << 4);
            *(half8*)(lb + off) = *(const half8*)(vg + (size_t)8 * j * 256);
        }
    }
    __syncthreads();

    // ---- PV: P fragments packed in-lane (layout matches A-frag by the key
    // permutation); V^T fragments from swizzled LDS
    float4v oacc[4];
    #pragma unroll
    for (int dt = 0; dt < 4; dt++) oacc[dt] = zf;
    __builtin_amdgcn_s_setprio(1);
    #pragma unroll
    for (int ks = 0; ks < 8; ks++) {
        half8 pf;
        #pragma unroll
        for (int r = 0; r < 4; r++) {
            pf[r]     = (_Float16)acc[2 * ks][r];
            pf[4 + r] = (_Float16)acc[2 * ks + 1][r];
        }
        const int vc = (ks * 64 + quad * 16) ^ swz;
        #pragma unroll
        for (int dt = 0; dt < 4; dt++) {
            half8 bv = *(const half8*)((const char*)KVs + (dt * 16 + lq) * 512 + vc);
            oacc[dt] = __builtin_amdgcn_mfma_f32_16x16x32_f16(pf, bv, oacc[dt], 0, 0, 0);
        }
    }
    __builtin_amdgcn_s_setprio(0);

    // ---- epilogue: fetch 1/l for row q=quad*4+r, write f16 in-place
    float linv = 1.f / l;
    float invr[4];
    #pragma unroll
    for (int r = 0; r < 4; r++) invr[r] = __shfl(linv, quad * 4 + r);
    #pragma unroll
    for (int dt = 0; dt < 4; dt++) {
        #pragma unroll
        for (int r = 0; r < 4; r++) {
            Oh[(size_t)(rbase + quad * 4 + r) * 1024 + qcol0 + dt * 16 + lq] =
                (_Float16)(oacc[dt][r] * invr[r]);
        }
    }
}

// ---------------------------------------------------- LayerNorm + re-quant ---
__global__ __launch_bounds__(256) void ln_quant(
    const _Float16* __restrict__ AO, const float* __restrict__ G,
    const float* __restrict__ Bt, signed char* __restrict__ O8,
    float* __restrict__ OS)
{
    int row = blockIdx.x * 4 + (threadIdx.x >> 6);
    int lane = threadIdx.x & 63;
    const _Float16* xr = AO + (size_t)row * 1024 + lane * 16;
    half8 h0 = *(const half8*)xr;
    half8 h1 = *(const half8*)(xr + 8);
    float x[16];
    #pragma unroll
    for (int i = 0; i < 8; i++) { x[i] = (float)h0[i]; x[8 + i] = (float)h1[i]; }
    float sx = 0.f, sx2 = 0.f;
    #pragma unroll
    for (int i = 0; i < 16; i++) { sx += x[i]; sx2 += x[i] * x[i]; }
    #pragma unroll
    for (int o = 32; o > 0; o >>= 1) {
        sx += __shfl_xor(sx, o);
        sx2 += __shfl_xor(sx2, o);
    }
    float mu = sx * (1.f / 1024.f);
    float var = sx2 * (1.f / 1024.f) - mu * mu;
    float rstd = 1.f / sqrtf(var + 1e-5f);

    const float4* gp = (const float4*)(G + lane * 16);
    const float4* bp = (const float4*)(Bt + lane * 16);
    float l[16];
    #pragma unroll
    for (int i = 0; i < 4; i++) {
        float4 gv = gp[i], bv = bp[i];
        l[i * 4 + 0] = (x[i * 4 + 0] - mu) * rstd * gv.x + bv.x;
        l[i * 4 + 1] = (x[i * 4 + 1] - mu) * rstd * gv.y + bv.y;
        l[i * 4 + 2] = (x[i * 4 + 2] - mu) * rstd * gv.z + bv.z;
        l[i * 4 + 3] = (x[i * 4 + 3] - mu) * rstd * gv.w + bv.w;
    }
    float msq = 0.f, am = 0.f;
    #pragma unroll
    for (int i = 0; i < 16; i++) { msq += l[i] * l[i]; am = fmaxf(am, fabsf(l[i])); }
    #pragma unroll
    for (int o = 32; o > 0; o >>= 1) {
        msq += __shfl_xor(msq, o);
        am = fmaxf(am, __shfl_xor(am, o));
    }
    float r2 = 1.f / sqrtf(msq * (1.f / 1024.f) + 1e-6f);
    float mx = fmaxf(am * r2, 1e-5f);
    float s = 127.f / mx;
    int pk[4];
    #pragma unroll
    for (int i = 0; i < 4; i++) {
        int q0 = quant8((l[i * 4 + 0] * r2) * s);
        int q1 = quant8((l[i * 4 + 1] * r2) * s);
        int q2 = quant8((l[i * 4 + 2] * r2) * s);
        int q3 = quant8((l[i * 4 + 3] * r2) * s);
        pk[i] = (q0 & 0xff) | ((q1 & 0xff) << 8) | ((q2 & 0xff) << 16) | ((q3 & 0xff) << 24);
    }
    int4v pv = {pk[0], pk[1], pk[2], pk[3]};
    ((int4v*)(O8 + (size_t)row * 1024))[lane] = pv;
    if (lane == 0) OS[row] = mx * (1.f / 127.f);
}

// ------------------------------------------------------------------ launch ---
extern "C" void kernel_launch(void* const* d_in, const int* in_sizes, int n_in,
                              void* d_out, int out_size, void* d_ws, size_t ws_size,
                              hipStream_t stream)
{
    const float* X  = (const float*)d_in[0];
    const float* Y  = (const float*)d_in[1];
    const float* WQ = (const float*)d_in[2];
    const float* WK = (const float*)d_in[3];
    const float* WV = (const float*)d_in[4];
    const float* WO = (const float*)d_in[5];
    const float* G  = (const float*)d_in[6];
    const float* Bt = (const float*)d_in[7];

    // workspace layout (~64 MB)
    char* ws = (char*)d_ws;
    double* part  = (double*)(ws + 256);               // 1536 B
    char* w8  = ws + 4096;                             // 3 MB (wq | wk+wv | wo)
    char* x8  = w8 + (3 << 20);                        // 16 MB (reused as o8)
    char* y8  = x8 + (16 << 20);                       // 4 MB
    float* xs = (float*)(y8 + (4 << 20));              // 64 KB
    float* ys = xs + 16384;                            // 16 KB
    float* os = ys + 4096;                             // 64 KB
    _Float16* qf16 = (_Float16*)(os + 16384);          // 32 MB (attn in-place)
    _Float16* kf16 = qf16 + (size_t)16384 * 1024;      // 4 MB
    _Float16* vt16 = kf16 + (size_t)4096 * 512;        // 4 MB
    char* wq8 = w8;
    char* kv8 = w8 + (1 << 20);
    char* wo8 = w8 + (2 << 20);
    char* o8  = x8;

    absmean_all<<<192, 256, 0, stream>>>(WQ, WK, WV, WO, part);

    prep_all<<<8192, 256, 0, stream>>>(
        WQ, WK, WV, WO, (signed char*)w8, part,
        X, (signed char*)x8, xs, Y, (signed char*)y8, ys);

    proj_fused<<<1280, 256, 0, stream>>>(
        (signed char*)x8, (signed char*)wq8, (signed char*)y8, (signed char*)kv8,
        qf16, kf16, vt16, xs, ys, part);

    attn_mfma<<<4096, 256, 0, stream>>>(qf16, kf16, vt16, qf16);

    ln_quant<<<4096, 256, 0, stream>>>(qf16, G, Bt, (signed char*)o8, os);

    gemm_out<<<dim3(8, 128), 256, 0, stream>>>(
        (signed char*)o8, (signed char*)wo8, (float*)d_out, os, part);
}

// Round 10
// 290.857 us; speedup vs baseline: 5.0759x; 1.0995x over previous
//
#include <hip/hip_runtime.h>
#include <hip/hip_bf16.h>

typedef int int4v __attribute__((ext_vector_type(4)));
typedef float float4v __attribute__((ext_vector_type(4)));
typedef _Float16 half8 __attribute__((ext_vector_type(8)));

#define DEV __device__ __forceinline__

DEV signed char quant8(float v) {
    int q = (int)rintf(v);
    q = q < -128 ? -128 : (q > 127 ? 127 : q);
    return (signed char)q;
}

DEV int tern1(float v) {
    int q = (int)rintf(v);
    q = q < -1 ? -1 : (q > 1 ? 1 : q);
    return q;
}

// async global->LDS, 16B per lane; LDS dest = wave-uniform base + lane*16
DEV void gl2lds16(const void* g, void* l) {
    __builtin_amdgcn_global_load_lds(
        (const __attribute__((address_space(1))) void*)g,
        (__attribute__((address_space(3))) void*)l, 16, 0, 0);
}

// wave-redundant absmean beta from the partial sums (no betas kernel)
DEV float beta_of(const double* __restrict__ part, int wi) {
    int offs = wi == 0 ? 0 : (wi == 1 ? 64 : (wi == 2 ? 96 : 128));
    int cnt  = (wi == 1 || wi == 2) ? 32 : 64;
    double invc = (wi == 1 || wi == 2) ? (1.0 / 524288.0) : (1.0 / 1048576.0);
    int lane = threadIdx.x & 63;
    double v = (lane < cnt) ? part[offs + lane] : 0.0;
    #pragma unroll
    for (int o = 32; o > 0; o >>= 1) v += __shfl_down(v, o);
    v = __shfl(v, 0);
    return fmaxf((float)(v * invc), 1e-5f);
}

// ---------------------------------------------------------------- weights ---
__global__ __launch_bounds__(256) void absmean_all(
    const float* __restrict__ WQ, const float* __restrict__ WK,
    const float* __restrict__ WV, const float* __restrict__ WO,
    double* __restrict__ part)
{
    __shared__ double red[256];
    int bx = blockIdx.x, t = threadIdx.x;
    const float* W; int rel;
    if (bx < 64)       { W = WQ; rel = bx; }
    else if (bx < 96)  { W = WK; rel = bx - 64; }
    else if (bx < 128) { W = WV; rel = bx - 96; }
    else               { W = WO; rel = bx - 128; }
    size_t base = (size_t)rel * 16384;
    double acc = 0.0;
    for (int i = t; i < 16384; i += 256) acc += (double)fabsf(W[base + i]);
    red[t] = acc; __syncthreads();
    #pragma unroll
    for (int o = 128; o > 0; o >>= 1) {
        if (t < o) red[t] += red[t + o];
        __syncthreads();
    }
    if (t == 0) part[bx] = red[0];
}

// --------------------------------------------- fused wquant + act_quant -----
DEV void act_row(const float* __restrict__ X, signed char* __restrict__ X8,
                 float* __restrict__ RS, int blk)
{
    int row = blk * 4 + (threadIdx.x >> 6);
    int lane = threadIdx.x & 63;
    const float4* xr = (const float4*)(X + (size_t)row * 1024) + lane * 4;
    float4 u[4];
    #pragma unroll
    for (int i = 0; i < 4; i++) u[i] = xr[i];
    float ss = 0.f, am = 0.f;
    #pragma unroll
    for (int i = 0; i < 4; i++) {
        ss += u[i].x * u[i].x + u[i].y * u[i].y + u[i].z * u[i].z + u[i].w * u[i].w;
        am = fmaxf(am, fmaxf(fmaxf(fabsf(u[i].x), fabsf(u[i].y)),
                             fmaxf(fabsf(u[i].z), fabsf(u[i].w))));
    }
    #pragma unroll
    for (int o = 32; o > 0; o >>= 1) {
        ss += __shfl_xor(ss, o);
        am = fmaxf(am, __shfl_xor(am, o));
    }
    float r = 1.f / sqrtf(ss * (1.f / 1024.f) + 1e-6f);
    float m = fmaxf(am * r, 1e-5f);
    float s = 127.f / m;
    int pk[4];
    #pragma unroll
    for (int i = 0; i < 4; i++) {
        int q0 = quant8((u[i].x * r) * s);
        int q1 = quant8((u[i].y * r) * s);
        int q2 = quant8((u[i].z * r) * s);
        int q3 = quant8((u[i].w * r) * s);
        pk[i] = (q0 & 0xff) | ((q1 & 0xff) << 8) | ((q2 & 0xff) << 16) | ((q3 & 0xff) << 24);
    }
    int4v pv = {pk[0], pk[1], pk[2], pk[3]};
    ((int4v*)(X8 + (size_t)row * 1024))[lane] = pv;
    if (lane == 0) RS[row] = m * (1.f / 127.f);
}

__global__ __launch_bounds__(256) void prep_all(
    const float* __restrict__ WQ, const float* __restrict__ WK,
    const float* __restrict__ WV, const float* __restrict__ WO,
    signed char* __restrict__ w8, const double* __restrict__ part,
    const float* __restrict__ X, signed char* __restrict__ X8, float* __restrict__ XS,
    const float* __restrict__ Y, signed char* __restrict__ Y8, float* __restrict__ YS)
{
    int bx = blockIdx.x;
    if (bx < 3072) {
        // ---- ternary weight quant (needs part[] from absmean)
        const float* W; signed char* O; int rel, wi;
        if (bx < 1024)      { W = WQ; O = w8;                           rel = bx;        wi = 0; }
        else if (bx < 1536) { W = WK; O = w8 + (1 << 20);               rel = bx - 1024; wi = 1; }
        else if (bx < 2048) { W = WV; O = w8 + (1 << 20) + (512 << 10); rel = bx - 1536; wi = 2; }
        else                { W = WO; O = w8 + (2 << 20);               rel = bx - 2048; wi = 3; }
        float inv = 1.f / beta_of(part, wi);
        int i = rel * 256 + threadIdx.x;
        float4 u = ((const float4*)W)[i];
        int q0 = tern1(u.x * inv);
        int q1 = tern1(u.y * inv);
        int q2 = tern1(u.z * inv);
        int q3 = tern1(u.w * inv);
        int packed = (q0 & 0xff) | ((q1 & 0xff) << 8) | ((q2 & 0xff) << 16) | ((q3 & 0xff) << 24);
        ((int*)O)[i] = packed;
    } else if (bx < 7168) {
        act_row(X, X8, XS, bx - 3072);     // 16384 rows
    } else {
        act_row(Y, Y8, YS, bx - 7168);     // 4096 rows
    }
}

// ------------------------------------------------------------------ GEMM ----
// C[M,N] = A[M,K](int8) . B[N,K](int8 ternary)^T, dequant rowscale*beta.
// 2-phase double-buffered K-loop (R3 known-good): stage(t+1) via
// global_load_lds before compute(t); ONE __syncthreads per K-step (its
// vmcnt(0) drain lands after the MFMAs). Betas computed in the prologue so
// their latency hides under the first staging barrier. mode is compile-time
// at each call site (dead branches eliminated).
DEV void gemm_core(
    signed char* As0, signed char* Bs0, signed char* As1, signed char* Bs1,
    const signed char* __restrict__ A, const signed char* __restrict__ B,
    float* __restrict__ outF, _Float16* __restrict__ outH,
    _Float16* __restrict__ outK, _Float16* __restrict__ outV,
    int N, int K,
    const float* __restrict__ rowscale, const double* __restrict__ part,
    int b0i, int b1i, int split, float extra, int mode,
    int bM, int bN)
{
    const int tid = threadIdx.x;
    const int lane = tid & 63, wid = tid >> 6;
    const int wr = wid >> 1, wc = wid & 1;
    const int lr = lane & 15, quad = lane >> 4;

    int4v zero = {0, 0, 0, 0};
    int4v acc[4][4];
    #pragma unroll
    for (int i = 0; i < 4; i++)
        #pragma unroll
        for (int j = 0; j < 4; j++) acc[i][j] = zero;

    const int srow = wid * 32 + (lane >> 2);
    const int soff = (lane & 3) * 16;
    const signed char* gA0 = A + (size_t)(bM * 128 + srow) * K + soff;
    const signed char* gA1 = gA0 + (size_t)16 * K;
    const signed char* gB0 = B + (size_t)(bN * 128 + srow) * K + soff;
    const signed char* gB1 = gB0 + (size_t)16 * K;
    const int lo0 = wid * 2048, lo1 = wid * 2048 + 1024;

    // prologue: stage k-tile 0 into buffer 0; betas overlap the staging
    gl2lds16(gA0, As0 + lo0);
    gl2lds16(gA1, As0 + lo1);
    gl2lds16(gB0, Bs0 + lo0);
    gl2lds16(gB1, Bs0 + lo1);
    const float s0 = beta_of(part, b0i) * extra;
    const float s1 = (b1i == b0i) ? s0 : beta_of(part, b1i) * extra;
    __syncthreads();

#define GEMM_COMPUTE(AS, BS)                                                   \
    {                                                                          \
        int4v af[4], bfr[4];                                                   \
        _Pragma("unroll")                                                      \
        for (int tm = 0; tm < 4; tm++)                                         \
            af[tm] = *(const int4v*)((AS) + (wr * 64 + tm * 16 + lr) * 64 + quad * 16); \
        _Pragma("unroll")                                                      \
        for (int tn = 0; tn < 4; tn++)                                         \
            bfr[tn] = *(const int4v*)((BS) + (wc * 64 + tn * 16 + lr) * 64 + quad * 16); \
        _Pragma("unroll")                                                      \
        for (int tm = 0; tm < 4; tm++)                                         \
            _Pragma("unroll")                                                  \
            for (int tn = 0; tn < 4; tn++)                                     \
                acc[tm][tn] = __builtin_amdgcn_mfma_i32_16x16x64_i8(af[tm], bfr[tn], acc[tm][tn], 0, 0, 0); \
    }

    for (int kb = 0; kb < K; kb += 128) {
        if (kb + 64 < K) {
            gl2lds16(gA0 + kb + 64, As1 + lo0);
            gl2lds16(gA1 + kb + 64, As1 + lo1);
            gl2lds16(gB0 + kb + 64, Bs1 + lo0);
            gl2lds16(gB1 + kb + 64, Bs1 + lo1);
        }
        GEMM_COMPUTE(As0, Bs0);
        __syncthreads();
        if (kb + 128 < K) {
            gl2lds16(gA0 + kb + 128, As0 + lo0);
            gl2lds16(gA1 + kb + 128, As0 + lo1);
            gl2lds16(gB0 + kb + 128, Bs0 + lo0);
            gl2lds16(gB1 + kb + 128, Bs0 + lo1);
        }
        GEMM_COMPUTE(As1, Bs1);
        __syncthreads();
    }
#undef GEMM_COMPUTE

    #pragma unroll
    for (int tm = 0; tm < 4; tm++) {
        #pragma unroll
        for (int r = 0; r < 4; r++) {
            int grow = bM * 128 + wr * 64 + tm * 16 + quad * 4 + r;
            float rs = rowscale[grow];
            #pragma unroll
            for (int tn = 0; tn < 4; tn++) {
                int col = bN * 128 + wc * 64 + tn * 16 + lr;
                float v = (float)acc[tm][tn][r] * rs * (col < split ? s0 : s1);
                if (mode == 0) {
                    outF[(size_t)grow * N + col] = v;
                } else if (mode == 1) {
                    outH[(size_t)grow * 1024 + col] = (_Float16)v;
                } else {
                    if (col < 512)
                        outK[(size_t)grow * 512 + col] = (_Float16)v;
                    else
                        outV[((size_t)(grow >> 8) * 512 + (col - 512)) * 256 + (grow & 255)] = (_Float16)v;
                }
            }
        }
    }
}

// fused q-projection (mode 1) + k/v-projection (mode 2) in one launch.
// Balanced per-XCD map: block b -> XCD x=b&7, slot s=b>>3. s<128 -> q-tile
// x*128+s (contiguous bM); s>=128 -> kv-tile x*32+(s-128).
// LDS padded to 40960 B -> HARD cap 4 blocks/CU (160/40), so only the
// first 1024 dispatched blocks (all q) are co-resident: per-XCD live set
// = 2MB A-chunk + 1MB wq8 = 3MB < 4MB L2 (R9's 4.5MB thrashed: FETCH
// 19->43.8MB, WRITE 41->92MB). kv blocks backfill as q retires with a
// 1.5MB L2-local set. launch_bounds min-waves can't cap occupancy; the
// LDS pad can.
__global__ __launch_bounds__(256) void proj_fused(
    const signed char* __restrict__ x8, const signed char* __restrict__ wq8,
    const signed char* __restrict__ y8, const signed char* __restrict__ kv8,
    _Float16* __restrict__ qf16, _Float16* __restrict__ kf16,
    _Float16* __restrict__ vt16,
    const float* __restrict__ xs, const float* __restrict__ ys,
    const double* __restrict__ part)
{
    __shared__ __align__(16) signed char As0[128 * 64 + 8192];  // +pad: occupancy cap
    __shared__ __align__(16) signed char Bs0[128 * 64];
    __shared__ __align__(16) signed char As1[128 * 64];
    __shared__ __align__(16) signed char Bs1[128 * 64];
    const int b = blockIdx.x;
    const int x = b & 7, s = b >> 3;
    if (s < 128) {
        int qi = x * 128 + s;
        gemm_core(As0, Bs0, As1, Bs1, x8, wq8, nullptr, qf16, nullptr, nullptr,
                  1024, 1024, xs, part, 0, 0, 1024, 0.125f, 1, qi >> 3, qi & 7);
    } else {
        int ki = x * 32 + (s - 128);
        gemm_core(As0, Bs0, As1, Bs1, y8, kv8, nullptr, nullptr, kf16, vt16,
                  1024, 1024, ys, part, 1, 2, 512, 1.f, 2, ki >> 3, ki & 7);
    }
}

// out projection (mode 0) -> f32
__global__ __launch_bounds__(256) void gemm_out(
    const signed char* __restrict__ A, const signed char* __restrict__ B,
    float* __restrict__ outF,
    const float* __restrict__ rowscale, const double* __restrict__ part)
{
    __shared__ __align__(16) signed char As0[128 * 64];
    __shared__ __align__(16) signed char Bs0[128 * 64];
    __shared__ __align__(16) signed char As1[128 * 64];
    __shared__ __align__(16) signed char Bs1[128 * 64];
    const int flat = blockIdx.y * 8 + blockIdx.x;
    const int chunk = (gridDim.x * gridDim.y) >> 3;
    const int f2 = (flat & 7) * chunk + (flat >> 3);
    gemm_core(As0, Bs0, As1, Bs1, A, B, outF, nullptr, nullptr, nullptr,
              1024, 1024, rowscale, part, 3, 3, 1024, 1.f, 0, f2 >> 3, f2 & 7);
}

// -------------------------------------------------------------- attention ---
// MFMA GQA, swapped-operand QK^T. Wave = 16 query rows of one (b,h,g).
// K tile staged with KEY-PERMUTED slot rows + XOR bank swizzle into a 32 KB
// region; V^T overlays the same region after QK^T. Swapped mfma(K,Q) puts a
// full 64-key slice of query q=lane&15 in-lane, so softmax is in-lane + 2
// shuffles, and the key permutation row(k)=(k&~31)|((k&4)<<2)|((k>>1)&12)|(k&3)
// makes the S^T C-layout coincide with PV's A-fragment layout: P is built by
// pure in-lane f32->f16 packing. No P LDS, no cross-lane P traffic.
// T5: setprio(1) around MFMA clusters.
__global__ __launch_bounds__(256, 4) void attn_mfma(
    const _Float16* Qh, const _Float16* __restrict__ Kh,
    const _Float16* __restrict__ Vt, _Float16* Oh)
{
    __shared__ __align__(16) _Float16 KVs[256 * 64];   // 32768 B; K then V^T overlay

    const int tid = threadIdx.x;
    const int lane = tid & 63;
    const int w = tid >> 6;
    const int lq = lane & 15;
    const int quad = lane >> 4;
    const int swz = (lq & 7) << 4;           // XOR bank swizzle (bytes)

    const int bx = blockIdx.x;               // b(16) x h(8) x g(2) x nt(16)
    const int nt = bx & 15, g = (bx >> 4) & 1, h = (bx >> 5) & 7, b = bx >> 8;
    const int rbase = b * 1024 + nt * 64 + w * 16;
    const int qcol0 = (h * 2 + g) * 64;

    // Q fragments (B-operand under swap), 1/8 scale folded in q-gemm epilogue
    half8 aq[2];
    #pragma unroll
    for (int ks = 0; ks < 2; ks++)
        aq[ks] = *(const half8*)(Qh + (size_t)(rbase + lq) * 1024 + qcol0 + ks * 32 + quad * 8);

    // ---- stage K tile: key kap -> permuted slot row, XOR-swizzled 16B chunks
    {
        int kb = tid >> 3;                   // kap & 31
        int c  = tid & 7;
        int rp = (kb & 3) | ((kb >> 1) & 12) | ((kb & 4) << 2);  // perm of 5 LSBs
        const _Float16* kg = Kh + (size_t)(b * 256 + kb) * 512 + h * 64 + c * 8;
        char* lb = (char*)KVs;
        #pragma unroll
        for (int j = 0; j < 8; j++) {
            int row = 32 * j + rp;
            int off = (row * 128 + c * 16) ^ ((row & 7) << 4);
            *(half8*)(lb + off) = *(const half8*)(kg + (size_t)32 * j * 512);
        }
    }
    __syncthreads();

    // ---- QK^T (swapped): acc[t] = mfma(Kfrag, Qfrag) -> S^T, lane holds
    // scores of query q=lq at keys (t>>1)*32 + quad*8 + (t&1)*4 + r
    float4v acc[16];
    float4v zf = {0.f, 0.f, 0.f, 0.f};
    #pragma unroll
    for (int t = 0; t < 16; t++) acc[t] = zf;
    const int kc0 = (quad * 16) ^ swz;
    const int kc1 = (64 + quad * 16) ^ swz;
    __builtin_amdgcn_s_setprio(1);
    #pragma unroll
    for (int t = 0; t < 16; t++) {
        const char* krow = (const char*)KVs + (t * 16 + lq) * 128;
        half8 kf0 = *(const half8*)(krow + kc0);
        acc[t] = __builtin_amdgcn_mfma_f32_16x16x32_f16(kf0, aq[0], acc[t], 0, 0, 0);
        half8 kf1 = *(const half8*)(krow + kc1);
        acc[t] = __builtin_amdgcn_mfma_f32_16x16x32_f16(kf1, aq[1], acc[t], 0, 0, 0);
    }
    __builtin_amdgcn_s_setprio(0);

    // ---- softmax for q=lq: in-lane over 64 keys + cross-quad combine
    float m = acc[0][0];
    #pragma unroll
    for (int t = 0; t < 16; t++) {
        #pragma unroll
        for (int r = 0; r < 4; r++) m = fmaxf(m, acc[t][r]);
    }
    m = fmaxf(m, __shfl_xor(m, 16));
    m = fmaxf(m, __shfl_xor(m, 32));
    float l = 0.f;
    #pragma unroll
    for (int t = 0; t < 16; t++) {
        #pragma unroll
        for (int r = 0; r < 4; r++) {
            float p = __expf(acc[t][r] - m);
            acc[t][r] = p;
            l += p;
        }
    }
    l += __shfl_xor(l, 16);
    l += __shfl_xor(l, 32);

    __syncthreads();   // all waves done reading K region

    // ---- stage V^T tile (64 x 256 f16), XOR-swizzled rows, overlays K
    {
        int row = tid >> 5, c = tid & 31;
        const _Float16* vg = Vt + ((size_t)b * 512 + h * 64 + row) * 256 + c * 8;
        char* lb = (char*)KVs;
        #pragma unroll
        for (int j = 0; j < 8; j++) {
            int rr = row + 8 * j;
            int off = (rr * 512 + c * 16) ^ ((rr & 7) << 4);
            *(half8*)(lb + off) = *(const half8*)(vg + (size_t)8 * j * 256);
        }
    }
    __syncthreads();

    // ---- PV: P fragments packed in-lane (layout matches A-frag by the key
    // permutation); V^T fragments from swizzled LDS
    float4v oacc[4];
    #pragma unroll
    for (int dt = 0; dt < 4; dt++) oacc[dt] = zf;
    __builtin_amdgcn_s_setprio(1);
    #pragma unroll
    for (int ks = 0; ks < 8; ks++) {
        half8 pf;
        #pragma unroll
        for (int r = 0; r < 4; r++) {
            pf[r]     = (_Float16)acc[2 * ks][r];
            pf[4 + r] = (_Float16)acc[2 * ks + 1][r];
        }
        const int vc = (ks * 64 + quad * 16) ^ swz;
        #pragma unroll
        for (int dt = 0; dt < 4; dt++) {
            half8 bv = *(const half8*)((const char*)KVs + (dt * 16 + lq) * 512 + vc);
            oacc[dt] = __builtin_amdgcn_mfma_f32_16x16x32_f16(pf, bv, oacc[dt], 0, 0, 0);
        }
    }
    __builtin_amdgcn_s_setprio(0);

    // ---- epilogue: fetch 1/l for row q=quad*4+r, write f16 in-place
    float linv = 1.f / l;
    float invr[4];
    #pragma unroll
    for (int r = 0; r < 4; r++) invr[r] = __shfl(linv, quad * 4 + r);
    #pragma unroll
    for (int dt = 0; dt < 4; dt++) {
        #pragma unroll
        for (int r = 0; r < 4; r++) {
            Oh[(size_t)(rbase + quad * 4 + r) * 1024 + qcol0 + dt * 16 + lq] =
                (_Float16)(oacc[dt][r] * invr[r]);
        }
    }
}

// ---------------------------------------------------- LayerNorm + re-quant ---
__global__ __launch_bounds__(256) void ln_quant(
    const _Float16* __restrict__ AO, const float* __restrict__ G,
    const float* __restrict__ Bt, signed char* __restrict__ O8,
    float* __restrict__ OS)
{
    int row = blockIdx.x * 4 + (threadIdx.x >> 6);
    int lane = threadIdx.x & 63;
    const _Float16* xr = AO + (size_t)row * 1024 + lane * 16;
    half8 h0 = *(const half8*)xr;
    half8 h1 = *(const half8*)(xr + 8);
    float x[16];
    #pragma unroll
    for (int i = 0; i < 8; i++) { x[i] = (float)h0[i]; x[8 + i] = (float)h1[i]; }
    float sx = 0.f, sx2 = 0.f;
    #pragma unroll
    for (int i = 0; i < 16; i++) { sx += x[i]; sx2 += x[i] * x[i]; }
    #pragma unroll
    for (int o = 32; o > 0; o >>= 1) {
        sx += __shfl_xor(sx, o);
        sx2 += __shfl_xor(sx2, o);
    }
    float mu = sx * (1.f / 1024.f);
    float var = sx2 * (1.f / 1024.f) - mu * mu;
    float rstd = 1.f / sqrtf(var + 1e-5f);

    const float4* gp = (const float4*)(G + lane * 16);
    const float4* bp = (const float4*)(Bt + lane * 16);
    float l[16];
    #pragma unroll
    for (int i = 0; i < 4; i++) {
        float4 gv = gp[i], bv = bp[i];
        l[i * 4 + 0] = (x[i * 4 + 0] - mu) * rstd * gv.x + bv.x;
        l[i * 4 + 1] = (x[i * 4 + 1] - mu) * rstd * gv.y + bv.y;
        l[i * 4 + 2] = (x[i * 4 + 2] - mu) * rstd * gv.z + bv.z;
        l[i * 4 + 3] = (x[i * 4 + 3] - mu) * rstd * gv.w + bv.w;
    }
    float msq = 0.f, am = 0.f;
    #pragma unroll
    for (int i = 0; i < 16; i++) { msq += l[i] * l[i]; am = fmaxf(am, fabsf(l[i])); }
    #pragma unroll
    for (int o = 32; o > 0; o >>= 1) {
        msq += __shfl_xor(msq, o);
        am = fmaxf(am, __shfl_xor(am, o));
    }
    float r2 = 1.f / sqrtf(msq * (1.f / 1024.f) + 1e-6f);
    float mx = fmaxf(am * r2, 1e-5f);
    float s = 127.f / mx;
    int pk[4];
    #pragma unroll
    for (int i = 0; i < 4; i++) {
        int q0 = quant8((l[i * 4 + 0] * r2) * s);
        int q1 = quant8((l[i * 4 + 1] * r2) * s);
        int q2 = quant8((l[i * 4 + 2] * r2) * s);
        int q3 = quant8((l[i * 4 + 3] * r2) * s);
        pk[i] = (q0 & 0xff) | ((q1 & 0xff) << 8) | ((q2 & 0xff) << 16) | ((q3 & 0xff) << 24);
    }
    int4v pv = {pk[0], pk[1], pk[2], pk[3]};
    ((int4v*)(O8 + (size_t)row * 1024))[lane] = pv;
    if (lane == 0) OS[row] = mx * (1.f / 127.f);
}

// ------------------------------------------------------------------ launch ---
extern "C" void kernel_launch(void* const* d_in, const int* in_sizes, int n_in,
                              void* d_out, int out_size, void* d_ws, size_t ws_size,
                              hipStream_t stream)
{
    const float* X  = (const float*)d_in[0];
    const float* Y  = (const float*)d_in[1];
    const float* WQ = (const float*)d_in[2];
    const float* WK = (const float*)d_in[3];
    const float* WV = (const float*)d_in[4];
    const float* WO = (const float*)d_in[5];
    const float* G  = (const float*)d_in[6];
    const float* Bt = (const float*)d_in[7];

    // workspace layout (~64 MB)
    char* ws = (char*)d_ws;
    double* part  = (double*)(ws + 256);               // 1536 B
    char* w8  = ws + 4096;                             // 3 MB (wq | wk+wv | wo)
    char* x8  = w8 + (3 << 20);                        // 16 MB (reused as o8)
    char* y8  = x8 + (16 << 20);                       // 4 MB
    float* xs = (float*)(y8 + (4 << 20));              // 64 KB
    float* ys = xs + 16384;                            // 16 KB
    float* os = ys + 4096;                             // 64 KB
    _Float16* qf16 = (_Float16*)(os + 16384);          // 32 MB (attn in-place)
    _Float16* kf16 = qf16 + (size_t)16384 * 1024;      // 4 MB
    _Float16* vt16 = kf16 + (size_t)4096 * 512;        // 4 MB
    char* wq8 = w8;
    char* kv8 = w8 + (1 << 20);
    char* wo8 = w8 + (2 << 20);
    char* o8  = x8;

    absmean_all<<<192, 256, 0, stream>>>(WQ, WK, WV, WO, part);

    prep_all<<<8192, 256, 0, stream>>>(
        WQ, WK, WV, WO, (signed char*)w8, part,
        X, (signed char*)x8, xs, Y, (signed char*)y8, ys);

    proj_fused<<<1280, 256, 0, stream>>>(
        (signed char*)x8, (signed char*)wq8, (signed char*)y8, (signed char*)kv8,
        qf16, kf16, vt16, xs, ys, part);

    attn_mfma<<<4096, 256, 0, stream>>>(qf16, kf16, vt16, qf16);

    ln_quant<<<4096, 256, 0, stream>>>(qf16, G, Bt, (signed char*)o8, os);

    gemm_out<<<dim3(8, 128), 256, 0, stream>>>(
        (signed char*)o8, (signed char*)wo8, (float*)d_out, os, part);
}

// Round 11
// 284.630 us; speedup vs baseline: 5.1870x; 1.0219x over previous
//
#include <hip/hip_runtime.h>
#include <hip/hip_bf16.h>

typedef int int4v __attribute__((ext_vector_type(4)));
typedef float float4v __attribute__((ext_vector_type(4)));
typedef _Float16 half8 __attribute__((ext_vector_type(8)));

#define DEV __device__ __forceinline__

DEV signed char quant8(float v) {
    int q = (int)rintf(v);
    q = q < -128 ? -128 : (q > 127 ? 127 : q);
    return (signed char)q;
}

DEV int tern1(float v) {
    int q = (int)rintf(v);
    q = q < -1 ? -1 : (q > 1 ? 1 : q);
    return q;
}

// async global->LDS, 16B per lane; LDS dest = wave-uniform base + lane*16
DEV void gl2lds16(const void* g, void* l) {
    __builtin_amdgcn_global_load_lds(
        (const __attribute__((address_space(1))) void*)g,
        (__attribute__((address_space(3))) void*)l, 16, 0, 0);
}

DEV void wait_vm4()   { asm volatile("s_waitcnt vmcnt(4)" ::: "memory"); }
DEV void wait_vm0()   { asm volatile("s_waitcnt vmcnt(0)" ::: "memory"); }
DEV void wait_lgkm0() { asm volatile("s_waitcnt lgkmcnt(0)" ::: "memory"); }

// wave-redundant absmean beta from the partial sums (no betas kernel)
DEV float beta_of(const double* __restrict__ part, int wi) {
    int offs = wi == 0 ? 0 : (wi == 1 ? 64 : (wi == 2 ? 96 : 128));
    int cnt  = (wi == 1 || wi == 2) ? 32 : 64;
    double invc = (wi == 1 || wi == 2) ? (1.0 / 524288.0) : (1.0 / 1048576.0);
    int lane = threadIdx.x & 63;
    double v = (lane < cnt) ? part[offs + lane] : 0.0;
    #pragma unroll
    for (int o = 32; o > 0; o >>= 1) v += __shfl_down(v, o);
    v = __shfl(v, 0);
    return fmaxf((float)(v * invc), 1e-5f);
}

// ---------------------------------------------------------------- weights ---
__global__ __launch_bounds__(256) void absmean_all(
    const float* __restrict__ WQ, const float* __restrict__ WK,
    const float* __restrict__ WV, const float* __restrict__ WO,
    double* __restrict__ part)
{
    __shared__ double red[256];
    int bx = blockIdx.x, t = threadIdx.x;
    const float* W; int rel;
    if (bx < 64)       { W = WQ; rel = bx; }
    else if (bx < 96)  { W = WK; rel = bx - 64; }
    else if (bx < 128) { W = WV; rel = bx - 96; }
    else               { W = WO; rel = bx - 128; }
    size_t base = (size_t)rel * 16384;
    double acc = 0.0;
    for (int i = t; i < 16384; i += 256) acc += (double)fabsf(W[base + i]);
    red[t] = acc; __syncthreads();
    #pragma unroll
    for (int o = 128; o > 0; o >>= 1) {
        if (t < o) red[t] += red[t + o];
        __syncthreads();
    }
    if (t == 0) part[bx] = red[0];
}

// --------------------------------------------- fused wquant + act_quant -----
DEV void act_row(const float* __restrict__ X, signed char* __restrict__ X8,
                 float* __restrict__ RS, int blk)
{
    int row = blk * 4 + (threadIdx.x >> 6);
    int lane = threadIdx.x & 63;
    const float4* xr = (const float4*)(X + (size_t)row * 1024) + lane * 4;
    float4 u[4];
    #pragma unroll
    for (int i = 0; i < 4; i++) u[i] = xr[i];
    float ss = 0.f, am = 0.f;
    #pragma unroll
    for (int i = 0; i < 4; i++) {
        ss += u[i].x * u[i].x + u[i].y * u[i].y + u[i].z * u[i].z + u[i].w * u[i].w;
        am = fmaxf(am, fmaxf(fmaxf(fabsf(u[i].x), fabsf(u[i].y)),
                             fmaxf(fabsf(u[i].z), fabsf(u[i].w))));
    }
    #pragma unroll
    for (int o = 32; o > 0; o >>= 1) {
        ss += __shfl_xor(ss, o);
        am = fmaxf(am, __shfl_xor(am, o));
    }
    float r = 1.f / sqrtf(ss * (1.f / 1024.f) + 1e-6f);
    float m = fmaxf(am * r, 1e-5f);
    float s = 127.f / m;
    int pk[4];
    #pragma unroll
    for (int i = 0; i < 4; i++) {
        int q0 = quant8((u[i].x * r) * s);
        int q1 = quant8((u[i].y * r) * s);
        int q2 = quant8((u[i].z * r) * s);
        int q3 = quant8((u[i].w * r) * s);
        pk[i] = (q0 & 0xff) | ((q1 & 0xff) << 8) | ((q2 & 0xff) << 16) | ((q3 & 0xff) << 24);
    }
    int4v pv = {pk[0], pk[1], pk[2], pk[3]};
    ((int4v*)(X8 + (size_t)row * 1024))[lane] = pv;
    if (lane == 0) RS[row] = m * (1.f / 127.f);
}

__global__ __launch_bounds__(256) void prep_all(
    const float* __restrict__ WQ, const float* __restrict__ WK,
    const float* __restrict__ WV, const float* __restrict__ WO,
    signed char* __restrict__ w8, const double* __restrict__ part,
    const float* __restrict__ X, signed char* __restrict__ X8, float* __restrict__ XS,
    const float* __restrict__ Y, signed char* __restrict__ Y8, float* __restrict__ YS)
{
    int bx = blockIdx.x;
    if (bx < 3072) {
        // ---- ternary weight quant (needs part[] from absmean)
        const float* W; signed char* O; int rel, wi;
        if (bx < 1024)      { W = WQ; O = w8;                           rel = bx;        wi = 0; }
        else if (bx < 1536) { W = WK; O = w8 + (1 << 20);               rel = bx - 1024; wi = 1; }
        else if (bx < 2048) { W = WV; O = w8 + (1 << 20) + (512 << 10); rel = bx - 1536; wi = 2; }
        else                { W = WO; O = w8 + (2 << 20);               rel = bx - 2048; wi = 3; }
        float inv = 1.f / beta_of(part, wi);
        int i = rel * 256 + threadIdx.x;
        float4 u = ((const float4*)W)[i];
        int q0 = tern1(u.x * inv);
        int q1 = tern1(u.y * inv);
        int q2 = tern1(u.z * inv);
        int q3 = tern1(u.w * inv);
        int packed = (q0 & 0xff) | ((q1 & 0xff) << 8) | ((q2 & 0xff) << 16) | ((q3 & 0xff) << 24);
        ((int*)O)[i] = packed;
    } else if (bx < 7168) {
        act_row(X, X8, XS, bx - 3072);     // 16384 rows
    } else {
        act_row(Y, Y8, YS, bx - 7168);     // 4096 rows
    }
}

// ------------------------------------------------------------------ GEMM ----
// C[M,N] = A[M,K](int8) . B[N,K](int8 ternary)^T, dequant rowscale*beta.
// 2-buffer K-loop with COUNTED vmcnt + raw barriers (T4, occupancy-safe):
//   vmcnt(4)  -> tile t resident; tile t+1's 4 loads STAY IN FLIGHT
//   s_barrier -> all waves see tile t
//   ds_read frags(t); lgkmcnt(0)+sched_barrier (reads landed)
//   s_barrier -> all waves done reading buf[t&1]
//   STAGE(t+2) -> buf[t&1]; then 16 MFMA cover the in-flight loads.
// vmcnt oldest-retire-first: at vmcnt(4), outstanding = tile t(4)+t+1(4);
// waiting to 4 retires exactly tile t. Last tile waits vmcnt(0). No
// vmcnt(0) drain in the steady-state loop (the ~R3 stall). 32KB LDS kept.
DEV void gemm_core(
    signed char* As0, signed char* Bs0, signed char* As1, signed char* Bs1,
    const signed char* __restrict__ A, const signed char* __restrict__ B,
    float* __restrict__ outF, _Float16* __restrict__ outH,
    _Float16* __restrict__ outK, _Float16* __restrict__ outV,
    int N, int K,
    const float* __restrict__ rowscale, const double* __restrict__ part,
    int b0i, int b1i, int split, float extra, int mode,
    int bM, int bN)
{
    const int tid = threadIdx.x;
    const int lane = tid & 63, wid = tid >> 6;
    const int wr = wid >> 1, wc = wid & 1;
    const int lr = lane & 15, quad = lane >> 4;

    int4v zero = {0, 0, 0, 0};
    int4v acc[4][4];
    #pragma unroll
    for (int i = 0; i < 4; i++)
        #pragma unroll
        for (int j = 0; j < 4; j++) acc[i][j] = zero;

    const int srow = wid * 32 + (lane >> 2);
    const int soff = (lane & 3) * 16;
    const signed char* gA0 = A + (size_t)(bM * 128 + srow) * K + soff;
    const signed char* gA1 = gA0 + (size_t)16 * K;
    const signed char* gB0 = B + (size_t)(bN * 128 + srow) * K + soff;
    const signed char* gB1 = gB0 + (size_t)16 * K;
    const int lo0 = wid * 2048, lo1 = wid * 2048 + 1024;

#define STAGE4(AS, BS, kb)                     \
    do {                                       \
        gl2lds16(gA0 + (kb), (AS) + lo0);      \
        gl2lds16(gA1 + (kb), (AS) + lo1);      \
        gl2lds16(gB0 + (kb), (BS) + lo0);      \
        gl2lds16(gB1 + (kb), (BS) + lo1);      \
    } while (0)

    // prologue: stage tiles 0 and 1; betas overlap the staging flight
    STAGE4(As0, Bs0, 0);
    STAGE4(As1, Bs1, 64);
    const float s0 = beta_of(part, b0i) * extra;
    const float s1 = (b1i == b0i) ? s0 : beta_of(part, b1i) * extra;

#define GEMM_STEP(AS, BS, LAST, DO_STAGE, KB2)                                 \
    {                                                                          \
        if (LAST) wait_vm0(); else wait_vm4();                                 \
        __builtin_amdgcn_s_barrier();                                          \
        int4v af[4], bfr[4];                                                   \
        _Pragma("unroll")                                                      \
        for (int tm = 0; tm < 4; tm++)                                         \
            af[tm] = *(const int4v*)((AS) + (wr * 64 + tm * 16 + lr) * 64 + quad * 16); \
        _Pragma("unroll")                                                      \
        for (int tn = 0; tn < 4; tn++)                                         \
            bfr[tn] = *(const int4v*)((BS) + (wc * 64 + tn * 16 + lr) * 64 + quad * 16); \
        wait_lgkm0();                                                          \
        __builtin_amdgcn_sched_barrier(0);                                     \
        __builtin_amdgcn_s_barrier();                                          \
        if (DO_STAGE) STAGE4(AS, BS, KB2);                                     \
        _Pragma("unroll")                                                      \
        for (int tm = 0; tm < 4; tm++)                                         \
            _Pragma("unroll")                                                  \
            for (int tn = 0; tn < 4; tn++)                                     \
                acc[tm][tn] = __builtin_amdgcn_mfma_i32_16x16x64_i8(af[tm], bfr[tn], acc[tm][tn], 0, 0, 0); \
    }

    for (int kb = 0; kb < K; kb += 128) {
        // sub-step A: tile kb in buf0
        GEMM_STEP(As0, Bs0, (kb + 64 >= K), (kb + 128 < K), kb + 128);
        // sub-step B: tile kb+64 in buf1
        if (kb + 64 < K)
            GEMM_STEP(As1, Bs1, (kb + 128 >= K), (kb + 192 < K), kb + 192);
    }
#undef GEMM_STEP
#undef STAGE4

    #pragma unroll
    for (int tm = 0; tm < 4; tm++) {
        #pragma unroll
        for (int r = 0; r < 4; r++) {
            int grow = bM * 128 + wr * 64 + tm * 16 + quad * 4 + r;
            float rs = rowscale[grow];
            #pragma unroll
            for (int tn = 0; tn < 4; tn++) {
                int col = bN * 128 + wc * 64 + tn * 16 + lr;
                float v = (float)acc[tm][tn][r] * rs * (col < split ? s0 : s1);
                if (mode == 0) {
                    outF[(size_t)grow * N + col] = v;
                } else if (mode == 1) {
                    outH[(size_t)grow * 1024 + col] = (_Float16)v;
                } else {
                    if (col < 512)
                        outK[(size_t)grow * 512 + col] = (_Float16)v;
                    else
                        outV[((size_t)(grow >> 8) * 512 + (col - 512)) * 256 + (grow & 255)] = (_Float16)v;
                }
            }
        }
    }
}

// fused q-projection (mode 1) + k/v-projection (mode 2) in one launch.
// Balanced per-XCD map: block b -> XCD x=b&7, slot s=b>>3. s<128 -> q-tile
// x*128+s (contiguous bM); s>=128 -> kv-tile x*32+(s-128).
// LDS padded to 40960 B -> HARD cap 4 blocks/CU: only the first 1024
// dispatched blocks (all q) co-resident -> per-XCD live set 3MB < 4MB L2
// (R9's 4.5MB thrashed; R10 fix measured FETCH 43.8->22.7MB, WRITE 92->41MB).
__global__ __launch_bounds__(256) void proj_fused(
    const signed char* __restrict__ x8, const signed char* __restrict__ wq8,
    const signed char* __restrict__ y8, const signed char* __restrict__ kv8,
    _Float16* __restrict__ qf16, _Float16* __restrict__ kf16,
    _Float16* __restrict__ vt16,
    const float* __restrict__ xs, const float* __restrict__ ys,
    const double* __restrict__ part)
{
    __shared__ __align__(16) signed char As0[128 * 64 + 8192];  // +pad: occupancy cap
    __shared__ __align__(16) signed char Bs0[128 * 64];
    __shared__ __align__(16) signed char As1[128 * 64];
    __shared__ __align__(16) signed char Bs1[128 * 64];
    const int b = blockIdx.x;
    const int x = b & 7, s = b >> 3;
    if (s < 128) {
        int qi = x * 128 + s;
        gemm_core(As0, Bs0, As1, Bs1, x8, wq8, nullptr, qf16, nullptr, nullptr,
                  1024, 1024, xs, part, 0, 0, 1024, 0.125f, 1, qi >> 3, qi & 7);
    } else {
        int ki = x * 32 + (s - 128);
        gemm_core(As0, Bs0, As1, Bs1, y8, kv8, nullptr, nullptr, kf16, vt16,
                  1024, 1024, ys, part, 1, 2, 512, 1.f, 2, ki >> 3, ki & 7);
    }
}

// out projection (mode 0) -> f32
__global__ __launch_bounds__(256) void gemm_out(
    const signed char* __restrict__ A, const signed char* __restrict__ B,
    float* __restrict__ outF,
    const float* __restrict__ rowscale, const double* __restrict__ part)
{
    __shared__ __align__(16) signed char As0[128 * 64];
    __shared__ __align__(16) signed char Bs0[128 * 64];
    __shared__ __align__(16) signed char As1[128 * 64];
    __shared__ __align__(16) signed char Bs1[128 * 64];
    const int flat = blockIdx.y * 8 + blockIdx.x;
    const int chunk = (gridDim.x * gridDim.y) >> 3;
    const int f2 = (flat & 7) * chunk + (flat >> 3);
    gemm_core(As0, Bs0, As1, Bs1, A, B, outF, nullptr, nullptr, nullptr,
              1024, 1024, rowscale, part, 3, 3, 1024, 1.f, 0, f2 >> 3, f2 & 7);
}

// -------------------------------------------------------------- attention ---
// MFMA GQA, swapped-operand QK^T. Wave = 16 query rows of one (b,h,g).
// K tile staged with KEY-PERMUTED slot rows + XOR bank swizzle into a 32 KB
// region; V^T overlays the same region after QK^T. Swapped mfma(K,Q) puts a
// full 64-key slice of query q=lane&15 in-lane, so softmax is in-lane + 2
// shuffles, and the key permutation row(k)=(k&~31)|((k&4)<<2)|((k>>1)&12)|(k&3)
// makes the S^T C-layout coincide with PV's A-fragment layout: P is built by
// pure in-lane f32->f16 packing. No P LDS, no cross-lane P traffic.
// T5: setprio(1) around MFMA clusters.
__global__ __launch_bounds__(256, 4) void attn_mfma(
    const _Float16* Qh, const _Float16* __restrict__ Kh,
    const _Float16* __restrict__ Vt, _Float16* Oh)
{
    __shared__ __align__(16) _Float16 KVs[256 * 64];   // 32768 B; K then V^T overlay

    const int tid = threadIdx.x;
    const int lane = tid & 63;
    const int w = tid >> 6;
    const int lq = lane & 15;
    const int quad = lane >> 4;
    const int swz = (lq & 7) << 4;           // XOR bank swizzle (bytes)

    const int bx = blockIdx.x;               // b(16) x h(8) x g(2) x nt(16)
    const int nt = bx & 15, g = (bx >> 4) & 1, h = (bx >> 5) & 7, b = bx >> 8;
    const int rbase = b * 1024 + nt * 64 + w * 16;
    const int qcol0 = (h * 2 + g) * 64;

    // Q fragments (B-operand under swap), 1/8 scale folded in q-gemm epilogue
    half8 aq[2];
    #pragma unroll
    for (int ks = 0; ks < 2; ks++)
        aq[ks] = *(const half8*)(Qh + (size_t)(rbase + lq) * 1024 + qcol0 + ks * 32 + quad * 8);

    // ---- stage K tile: key kap -> permuted slot row, XOR-swizzled 16B chunks
    {
        int kb = tid >> 3;                   // kap & 31
        int c  = tid & 7;
        int rp = (kb & 3) | ((kb >> 1) & 12) | ((kb & 4) << 2);  // perm of 5 LSBs
        const _Float16* kg = Kh + (size_t)(b * 256 + kb) * 512 + h * 64 + c * 8;
        char* lb = (char*)KVs;
        #pragma unroll
        for (int j = 0; j < 8; j++) {
            int row = 32 * j + rp;
            int off = (row * 128 + c * 16) ^ ((row & 7) << 4);
            *(half8*)(lb + off) = *(const half8*)(kg + (size_t)32 * j * 512);
        }
    }
    __syncthreads();

    // ---- QK^T (swapped): acc[t] = mfma(Kfrag, Qfrag) -> S^T, lane holds
    // scores of query q=lq at keys (t>>1)*32 + quad*8 + (t&1)*4 + r
    float4v acc[16];
    float4v zf = {0.f, 0.f, 0.f, 0.f};
    #pragma unroll
    for (int t = 0; t < 16; t++) acc[t] = zf;
    const int kc0 = (quad * 16) ^ swz;
    const int kc1 = (64 + quad * 16) ^ swz;
    __builtin_amdgcn_s_setprio(1);
    #pragma unroll
    for (int t = 0; t < 16; t++) {
        const char* krow = (const char*)KVs + (t * 16 + lq) * 128;
        half8 kf0 = *(const half8*)(krow + kc0);
        acc[t] = __builtin_amdgcn_mfma_f32_16x16x32_f16(kf0, aq[0], acc[t], 0, 0, 0);
        half8 kf1 = *(const half8*)(krow + kc1);
        acc[t] = __builtin_amdgcn_mfma_f32_16x16x32_f16(kf1, aq[1], acc[t], 0, 0, 0);
    }
    __builtin_amdgcn_s_setprio(0);

    // ---- softmax for q=lq: in-lane over 64 keys + cross-quad combine
    float m = acc[0][0];
    #pragma unroll
    for (int t = 0; t < 16; t++) {
        #pragma unroll
        for (int r = 0; r < 4; r++) m = fmaxf(m, acc[t][r]);
    }
    m = fmaxf(m, __shfl_xor(m, 16));
    m = fmaxf(m, __shfl_xor(m, 32));
    float l = 0.f;
    #pragma unroll
    for (int t = 0; t < 16; t++) {
        #pragma unroll
        for (int r = 0; r < 4; r++) {
            float p = __expf(acc[t][r] - m);
            acc[t][r] = p;
            l += p;
        }
    }
    l += __shfl_xor(l, 16);
    l += __shfl_xor(l, 32);

    __syncthreads();   // all waves done reading K region

    // ---- stage V^T tile (64 x 256 f16), XOR-swizzled rows, overlays K
    {
        int row = tid >> 5, c = tid & 31;
        const _Float16* vg = Vt + ((size_t)b * 512 + h * 64 + row) * 256 + c * 8;
        char* lb = (char*)KVs;
        #pragma unroll
        for (int j = 0; j < 8; j++) {
            int rr = row + 8 * j;
            int off = (rr * 512 + c * 16) ^ ((rr & 7) << 4);
            *(half8*)(lb + off) = *(const half8*)(vg + (size_t)8 * j * 256);
        }
    }
    __syncthreads();

    // ---- PV: P fragments packed in-lane (layout matches A-frag by the key
    // permutation); V^T fragments from swizzled LDS
    float4v oacc[4];
    #pragma unroll
    for (int dt = 0; dt < 4; dt++) oacc[dt] = zf;
    __builtin_amdgcn_s_setprio(1);
    #pragma unroll
    for (int ks = 0; ks < 8; ks++) {
        half8 pf;
        #pragma unroll
        for (int r = 0; r < 4; r++) {
            pf[r]     = (_Float16)acc[2 * ks][r];
            pf[4 + r] = (_Float16)acc[2 * ks + 1][r];
        }
        const int vc = (ks * 64 + quad * 16) ^ swz;
        #pragma unroll
        for (int dt = 0; dt < 4; dt++) {
            half8 bv = *(const half8*)((const char*)KVs + (dt * 16 + lq) * 512 + vc);
            oacc[dt] = __builtin_amdgcn_mfma_f32_16x16x32_f16(pf, bv, oacc[dt], 0, 0, 0);
        }
    }
    __builtin_amdgcn_s_setprio(0);

    // ---- epilogue: fetch 1/l for row q=quad*4+r, write f16 in-place
    float linv = 1.f / l;
    float invr[4];
    #pragma unroll
    for (int r = 0; r < 4; r++) invr[r] = __shfl(linv, quad * 4 + r);
    #pragma unroll
    for (int dt = 0; dt < 4; dt++) {
        #pragma unroll
        for (int r = 0; r < 4; r++) {
            Oh[(size_t)(rbase + quad * 4 + r) * 1024 + qcol0 + dt * 16 + lq] =
                (_Float16)(oacc[dt][r] * invr[r]);
        }
    }
}

// ---------------------------------------------------- LayerNorm + re-quant ---
__global__ __launch_bounds__(256) void ln_quant(
    const _Float16* __restrict__ AO, const float* __restrict__ G,
    const float* __restrict__ Bt, signed char* __restrict__ O8,
    float* __restrict__ OS)
{
    int row = blockIdx.x * 4 + (threadIdx.x >> 6);
    int lane = threadIdx.x & 63;
    const _Float16* xr = AO + (size_t)row * 1024 + lane * 16;
    half8 h0 = *(const half8*)xr;
    half8 h1 = *(const half8*)(xr + 8);
    float x[16];
    #pragma unroll
    for (int i = 0; i < 8; i++) { x[i] = (float)h0[i]; x[8 + i] = (float)h1[i]; }
    float sx = 0.f, sx2 = 0.f;
    #pragma unroll
    for (int i = 0; i < 16; i++) { sx += x[i]; sx2 += x[i] * x[i]; }
    #pragma unroll
    for (int o = 32; o > 0; o >>= 1) {
        sx += __shfl_xor(sx, o);
        sx2 += __shfl_xor(sx2, o);
    }
    float mu = sx * (1.f / 1024.f);
    float var = sx2 * (1.f / 1024.f) - mu * mu;
    float rstd = 1.f / sqrtf(var + 1e-5f);

    const float4* gp = (const float4*)(G + lane * 16);
    const float4* bp = (const float4*)(Bt + lane * 16);
    float l[16];
    #pragma unroll
    for (int i = 0; i < 4; i++) {
        float4 gv = gp[i], bv = bp[i];
        l[i * 4 + 0] = (x[i * 4 + 0] - mu) * rstd * gv.x + bv.x;
        l[i * 4 + 1] = (x[i * 4 + 1] - mu) * rstd * gv.y + bv.y;
        l[i * 4 + 2] = (x[i * 4 + 2] - mu) * rstd * gv.z + bv.z;
        l[i * 4 + 3] = (x[i * 4 + 3] - mu) * rstd * gv.w + bv.w;
    }
    float msq = 0.f, am = 0.f;
    #pragma unroll
    for (int i = 0; i < 16; i++) { msq += l[i] * l[i]; am = fmaxf(am, fabsf(l[i])); }
    #pragma unroll
    for (int o = 32; o > 0; o >>= 1) {
        msq += __shfl_xor(msq, o);
        am = fmaxf(am, __shfl_xor(am, o));
    }
    float r2 = 1.f / sqrtf(msq * (1.f / 1024.f) + 1e-6f);
    float mx = fmaxf(am * r2, 1e-5f);
    float s = 127.f / mx;
    int pk[4];
    #pragma unroll
    for (int i = 0; i < 4; i++) {
        int q0 = quant8((l[i * 4 + 0] * r2) * s);
        int q1 = quant8((l[i * 4 + 1] * r2) * s);
        int q2 = quant8((l[i * 4 + 2] * r2) * s);
        int q3 = quant8((l[i * 4 + 3] * r2) * s);
        pk[i] = (q0 & 0xff) | ((q1 & 0xff) << 8) | ((q2 & 0xff) << 16) | ((q3 & 0xff) << 24);
    }
    int4v pv = {pk[0], pk[1], pk[2], pk[3]};
    ((int4v*)(O8 + (size_t)row * 1024))[lane] = pv;
    if (lane == 0) OS[row] = mx * (1.f / 127.f);
}

// ------------------------------------------------------------------ launch ---
extern "C" void kernel_launch(void* const* d_in, const int* in_sizes, int n_in,
                              void* d_out, int out_size, void* d_ws, size_t ws_size,
                              hipStream_t stream)
{
    const float* X  = (const float*)d_in[0];
    const float* Y  = (const float*)d_in[1];
    const float* WQ = (const float*)d_in[2];
    const float* WK = (const float*)d_in[3];
    const float* WV = (const float*)d_in[4];
    const float* WO = (const float*)d_in[5];
    const float* G  = (const float*)d_in[6];
    const float* Bt = (const float*)d_in[7];

    // workspace layout (~64 MB)
    char* ws = (char*)d_ws;
    double* part  = (double*)(ws + 256);               // 1536 B
    char* w8  = ws + 4096;                             // 3 MB (wq | wk+wv | wo)
    char* x8  = w8 + (3 << 20);                        // 16 MB (reused as o8)
    char* y8  = x8 + (16 << 20);                       // 4 MB
    float* xs = (float*)(y8 + (4 << 20));              // 64 KB
    float* ys = xs + 16384;                            // 16 KB
    float* os = ys + 4096;                             // 64 KB
    _Float16* qf16 = (_Float16*)(os + 16384);          // 32 MB (attn in-place)
    _Float16* kf16 = qf16 + (size_t)16384 * 1024;      // 4 MB
    _Float16* vt16 = kf16 + (size_t)4096 * 512;        // 4 MB
    char* wq8 = w8;
    char* kv8 = w8 + (1 << 20);
    char* wo8 = w8 + (2 << 20);
    char* o8  = x8;

    absmean_all<<<192, 256, 0, stream>>>(WQ, WK, WV, WO, part);

    prep_all<<<8192, 256, 0, stream>>>(
        WQ, WK, WV, WO, (signed char*)w8, part,
        X, (signed char*)x8, xs, Y, (signed char*)y8, ys);

    proj_fused<<<1280, 256, 0, stream>>>(
        (signed char*)x8, (signed char*)wq8, (signed char*)y8, (signed char*)kv8,
        qf16, kf16, vt16, xs, ys, part);

    attn_mfma<<<4096, 256, 0, stream>>>(qf16, kf16, vt16, qf16);

    ln_quant<<<4096, 256, 0, stream>>>(qf16, G, Bt, (signed char*)o8, os);

    gemm_out<<<dim3(8, 128), 256, 0, stream>>>(
        (signed char*)o8, (signed char*)wo8, (float*)d_out, os, part);
}